// Round 9
// baseline (1069.354 us; speedup 1.0000x reference)
//
#include <hip/hip_runtime.h>
#include <cstdint>
#include <cstddef>

typedef unsigned short u16;
typedef __attribute__((ext_vector_type(8))) short short8;
typedef __attribute__((ext_vector_type(4))) short short4v;
typedef __attribute__((ext_vector_type(4))) float f32x4;

__device__ __forceinline__ float b2f(u16 u){ return __uint_as_float(((unsigned)u)<<16); }
__device__ __forceinline__ u16 f2b(float f){
    unsigned u = __float_as_uint(f);
    return (u16)((u + 0x7fffu + ((u>>16)&1u)) >> 16);
}
__device__ __forceinline__ int iclamp(int v, int lo, int hi){ return v<lo?lo:(v>hi?hi:v); }

// LDS-only barrier: no vmcnt(0) drain (global loads/stores stay in flight)
__device__ __forceinline__ void barrier_lds(){
    asm volatile("s_waitcnt lgkmcnt(0)\n\ts_barrier" ::: "memory");
}

__device__ __forceinline__ float fast_exp2(float x){
#if __has_builtin(__builtin_amdgcn_exp2f)
    return __builtin_amdgcn_exp2f(x);
#else
    return __expf(x * 0.6931471805599453f);
#endif
}

// 8-wide f32 -> bf16 fragment
__device__ __forceinline__ short8 ld8f(const float* p){
    f32x4 a = *(const f32x4*)p;
    f32x4 b = *(const f32x4*)(p+4);
    short8 r;
    #pragma unroll
    for(int j=0;j<4;j++){ r[j]=(short)f2b(a[j]); r[4+j]=(short)f2b(b[j]); }
    return r;
}
// scaled variant: round(s*W) — single bf16 rounding, same error class as round(W)
__device__ __forceinline__ short8 ld8f_s(const float* p, float s){
    f32x4 a = *(const f32x4*)p;
    f32x4 b = *(const f32x4*)(p+4);
    short8 r;
    #pragma unroll
    for(int j=0;j<4;j++){ r[j]=(short)f2b(a[j]*s); r[4+j]=(short)f2b(b[j]*s); }
    return r;
}
__device__ __forceinline__ short8 ld8b(const u16* p){ return *(const short8*)p; }

// tanh scale constant: 2*log2(e); tanh(v) = 1 - 2*rcp(exp2(c*v)+1)
#define C_TANH 2.8853900817779268f

// ====== device-scope grid barrier for the 256-block megakernel ======
// All 256 blocks guaranteed co-resident (256 CUs, 20.5KB LDS, 256 thr/block).
// __threadfence() provides agent-scope release/acquire (L2 writeback/invalidate
// across XCDs — required since tmpT/hbuf are rewritten and re-read across stages).
__device__ __forceinline__ void gsync(unsigned* cnt, unsigned target){
    __syncthreads();
    __threadfence();                               // release: drain + writeback
    if(threadIdx.x==0){
        atomicAdd(cnt, 1u);                        // device-scope by default
        while(__hip_atomic_load(cnt, __ATOMIC_RELAXED, __HIP_MEMORY_SCOPE_AGENT) < target){
            __builtin_amdgcn_s_sleep(2);
        }
    }
    __syncthreads();
    __threadfence();                               // acquire: invalidate L1/L2
}

// =============== 64x64-tile BT GEMM stage body (2-deep prefetch, dbuf LDS) ======
// C(MxN) = A(MxK) @ B(NxK)^T (+bias f32), bf16 out.  bx in [0,M/64), by in [0,N/64).
template<bool TRANSOUT, bool RELU, bool AF32, bool BF32>
__device__ __forceinline__ void gemm_dev(
    const void* __restrict__ A, const void* __restrict__ B,
    const float* __restrict__ bias, u16* __restrict__ C,
    int M, int N, int K, int ldb, int ldc, int bx, int by,
    u16 (&As)[2][64][40], u16 (&Bs)[2][64][40])
{
    constexpr int BK=32;
    const int tid = threadIdx.x;
    const int bm = bx*64, bn = by*64;
    const int wave = tid>>6, lane = tid&63, lm = lane&15, lg = lane>>4;
    const int wm = (wave>>1)*32, wn = (wave&1)*32;
    f32x4 acc[2][2];
    #pragma unroll
    for(int i=0;i<2;i++){ acc[i][0]=(f32x4){0.f,0.f,0.f,0.f}; acc[i][1]=(f32x4){0.f,0.f,0.f,0.f}; }

    const int arow = tid>>2, akc = (tid&3)*8;
    auto lda8 = [&](int k)->short8{
        return AF32 ? ld8f((const float*)A + (size_t)(bm+arow)*K + k+akc)
                    : ld8b((const u16*)A + (size_t)(bm+arow)*K + k+akc);
    };
    auto ldb8v = [&](int k)->short8{
        return BF32 ? ld8f((const float*)B + (size_t)(bn+arow)*ldb + k+akc)
                    : ld8b((const u16*)B + (size_t)(bn+arow)*ldb + k+akc);
    };
    // prologue: tile0 -> LDS buf0; tile1 -> regs (in flight across iter 0)
    *(short8*)&As[0][arow][akc] = lda8(0);
    *(short8*)&Bs[0][arow][akc] = ldb8v(0);
    short8 a_hold, b_hold;
    if(BK < K){ a_hold = lda8(BK); b_hold = ldb8v(BK); }
    barrier_lds();
    int p = 0;
    for(int k0=0;k0<K;k0+=BK){
        short8 a_next, b_next;
        const bool have2 = (k0+2*BK < K);
        if(have2){ a_next = lda8(k0+2*BK); b_next = ldb8v(k0+2*BK); }
        short8 af[2], bfg[2];
        #pragma unroll
        for(int mt=0;mt<2;mt++) af[mt]  = *(const short8*)&As[p][wm+mt*16+lm][lg*8];
        #pragma unroll
        for(int nt=0;nt<2;nt++) bfg[nt] = *(const short8*)&Bs[p][wn+nt*16+lm][lg*8];
        if(k0+BK < K){   // write tile i+1 (loaded a full iter ago) into the other buffer
            *(short8*)&As[p^1][arow][akc] = a_hold;
            *(short8*)&Bs[p^1][arow][akc] = b_hold;
        }
        #pragma unroll
        for(int nt=0;nt<2;nt++)
            #pragma unroll
            for(int mt=0;mt<2;mt++)
                acc[mt][nt] = __builtin_amdgcn_mfma_f32_16x16x32_bf16(af[mt], bfg[nt], acc[mt][nt], 0,0,0);
        barrier_lds();
        a_hold = a_next; b_hold = b_next;
        p ^= 1;
    }
    #pragma unroll
    for(int nt=0;nt<2;nt++){
        const int col = bn+wn+nt*16+lm;
        const float bv = bias ? bias[col] : 0.f;
        #pragma unroll
        for(int mt=0;mt<2;mt++){
            const int row0 = bm+wm+mt*16+lg*4;
            #pragma unroll
            for(int r=0;r<4;r++){
                const int row = row0+r;
                float v = acc[mt][nt][r] + bv;
                if(RELU) v = fmaxf(v, 0.f);
                const size_t idx = TRANSOUT ? ((size_t)col*ldc + row) : ((size_t)row*ldc + col);
                C[idx] = f2b(v);
            }
        }
    }
}

// ====== k_mega: g1..g5 + k_pre in ONE launch, grid-barrier between stages ======
// 256 blocks (bx=bid&63 row-tile, by=bid>>6 col-tile for every gemm stage).
// Removes 5 kernel boundaries (launch gap + drain + cache flush each).
__global__ __launch_bounds__(256) void k_mega(
    const float* __restrict__ stu, const float* __restrict__ hg_w1, const float* __restrict__ hg_b1,
    const u16* __restrict__ Gb, const float* __restrict__ hg_w2, const float* __restrict__ hg_b2,
    const float* __restrict__ hgr_wih,
    u16* __restrict__ tmpT, u16* __restrict__ hbuf, u16* __restrict__ stu_proj,
    const int* __restrict__ combo_t, const int* __restrict__ sid_t,
    const float* __restrict__ table_dg, const float* __restrict__ table_hg,
    const u16* __restrict__ pooled_proj,
    u16* __restrict__ pre_dg, u16* __restrict__ pre_hg,
    unsigned* __restrict__ cnt)
{
    __shared__ u16 As[2][64][40];
    __shared__ u16 Bs[2][64][40];
    const int bid = blockIdx.x;
    const int bx = bid & 63, by = bid >> 6;

    gemm_dev<true ,false,true ,true >(stu,  hg_w1, hg_b1, tmpT, 4096,256,256,  256, 4096, bx,by, As,Bs);
    gsync(cnt, 256);
    gemm_dev<false,true ,false,false>(Gb,   tmpT,  nullptr, hbuf, 4096,256,4096, 4096, 256, bx,by, As,Bs);
    gsync(cnt, 512);
    gemm_dev<true ,false,false,true >(hbuf, hg_w2, hg_b2, tmpT, 4096,256,256,  256, 4096, bx,by, As,Bs);
    gsync(cnt, 768);
    gemm_dev<false,false,false,false>(Gb,   tmpT,  nullptr, hbuf, 4096,256,4096, 4096, 256, bx,by, As,Bs);
    gsync(cnt, 1024);
    gemm_dev<false,false,false,true >(hbuf, hgr_wih, nullptr, stu_proj, 4096,256,256, 768, 256, bx,by, As,Bs);
    gsync(cnt, 1280);

    // stage 6: k_pre redistributed — 250 (rnn,t,b) row-tasks per block, c = tid.
    // Values bit-identical to the old k_pre: (table[cmb][c] + proj[c]) * C_TANH.
    const int c = threadIdx.x;
    int tt = bid*250;
    int rnn = tt/32000, r = tt - rnn*32000;
    for(int i=0;i<250;i++){
        const int t = r>>6, b = r&63;
        const int cmb = combo_t[t*64+b];
        const float* tab = rnn ? table_hg : table_dg;
        const u16* prow = rnn ? (stu_proj + (size_t)sid_t[t*64+b]*256)
                              : (pooled_proj + (size_t)b*256);
        u16* outp = rnn ? pre_hg : pre_dg;
        const float v = (tab[(size_t)cmb*256 + c] + b2f(prow[c])) * C_TANH;
        outp[((size_t)t*64+b)*256 + c] = f2b(v);
        if(++r == 32000){ r = 0; rnn = 1; }
    }
}

// ====== k_prep: fused independent prep — tables (606) + idx (125) + h1pre (8) + G cvt (8192) ======
// Also zeroes the megakernel's grid-barrier counter each graph replay.
__global__ __launch_bounds__(256) void k_prep(
    const float* __restrict__ skill_emb, const float* __restrict__ answer_emb,
    const float* __restrict__ wih_dg, const float* __restrict__ bih_dg, const float* __restrict__ bhh_dg,
    const float* __restrict__ wih_hg, const float* __restrict__ bih_hg, const float* __restrict__ bhh_hg,
    const float* __restrict__ gcn_w1,
    const int* __restrict__ skill, const int* __restrict__ answer, const int* __restrict__ student,
    const float* __restrict__ G, u16* __restrict__ Gb,
    float* __restrict__ table_dg, float* __restrict__ table_hg,
    float* __restrict__ h1pre, int* __restrict__ combo_t, int* __restrict__ sid_t,
    unsigned* __restrict__ cnt)
{
    const int bid = blockIdx.x, tid = threadIdx.x;
    if(bid==0 && tid==0) *cnt = 0u;
    if(bid < 606){
        // table part: table[combo] = x(skill,answer) @ Wih[:,256:768]^T + bih + bhh
        const int which = (bid >= 303) ? 1 : 0;
        const int combo = bid - which*303;
        const float* wih = which ? wih_hg : wih_dg;
        const float* bih = which ? bih_hg : bih_dg;
        const float* bhh = which ? bhh_hg : bhh_dg;
        float* table     = which ? table_hg : table_dg;
        const int sid = combo/3, ans = combo - sid*3;
        __shared__ float sf[256], sg[256];
        sf[tid] = (ans==1) ? skill_emb[(size_t)sid*256+tid] : answer_emb[(size_t)ans*256+tid];
        sg[tid] = (ans==1) ? answer_emb[(size_t)ans*256+tid] : skill_emb[(size_t)sid*256+tid];
        __syncthreads();
        const int o = tid;
        float acc = bih[o] + bhh[o];
        const float* w = wih + (size_t)o*768;
        for(int k=0;k<256;k+=4){
            f32x4 w1v = *(const f32x4*)&w[256+k];
            f32x4 w2v = *(const f32x4*)&w[512+k];
            acc += sf[k]*w1v.x + sf[k+1]*w1v.y + sf[k+2]*w1v.z + sf[k+3]*w1v.w;
            acc += sg[k]*w2v.x + sg[k+1]*w2v.y + sg[k+2]*w2v.z + sg[k+3]*w2v.w;
        }
        table[(size_t)combo*256 + o] = acc;
    } else if(bid < 731){
        // idx part: combo/sid arrays, t-major, clamped
        const int i = (bid-606)*256 + tid;
        if(i>=32000) return;
        const int t = i>>6, b = i&63;
        const int sk = iclamp(skill[b*500+t], 0, 100);
        const int an = iclamp(answer[b*500+t], 0, 2);
        const int sd = iclamp(student[b*500+t]-1, 0, 4095);
        combo_t[i] = sk*3+an;
        sid_t[i]   = sd;
    } else if(bid < 739){
        // h1pre part: skill_emb @ gcn_w1^T (101x8)
        if(tid >= 101) return;
        const int idx = (bid-731)*101 + tid;
        if(idx>=808) return;
        const int n=idx>>3, j=idx&7;
        const float* x = skill_emb + n*256;
        const float* w = gcn_w1 + j*256;
        float acc=0.f;
        for(int k=0;k<256;k+=4){
            f32x4 a = *(const f32x4*)&x[k];
            f32x4 b = *(const f32x4*)&w[k];
            acc += a.x*b.x + a.y*b.y + a.z*b.z + a.w*b.w;
        }
        h1pre[idx]=acc;
    } else {
        // G cvt part: f32 -> bf16, 4096x4096 (8192 blocks x 2048 elems)
        const size_t i = ((size_t)(bid-739)*256 + tid)*8;
        *(short8*)&Gb[i] = ld8f(G + i);
    }
}

// =============== per-batch skill GCN + softmax pooling + fused dg_wih projection ======
// -> pooled_proj (bf16 64x256). pooled row never leaves the block (LDS red[]).
__global__ __launch_bounds__(256) void k_gcn(
    const int* __restrict__ skill, const int* __restrict__ answer,
    const float* __restrict__ pos, const float* __restrict__ h1pre,
    const float* __restrict__ gcn_b1, const float* __restrict__ gcn_w2, const float* __restrict__ gcn_b2,
    const float* __restrict__ wih_dg,
    u16* __restrict__ pooled_proj)
{
    const int b = blockIdx.x, tid = threadIdx.x;
    __shared__ int   sk[500];
    __shared__ float msk[500];
    __shared__ float coef[500];
    __shared__ float deg[101];
    __shared__ float agg1[101*8];
    __shared__ float agg2[101*8];
    __shared__ float red[256];
    __shared__ float vec8[8];
    __shared__ float sS[1];

    for(int i=tid;i<500;i+=256){
        sk[i]=iclamp(skill[b*500+i],0,100);
        msk[i] = (answer[b*500+i]!=2)?1.f:0.f;
    }
    for(int i=tid;i<101;i+=256) deg[i]=1.f;           // self loop
    if(tid<8)  vec8[tid]=0.f;
    if(tid==8) sS[0]=0.f;
    __syncthreads();
    for(int e=tid;e<499;e+=256) atomicAdd(&deg[sk[e+1]], 1.f);
    __syncthreads();
    for(int i=tid;i<101;i+=256) deg[i] = rsqrtf(deg[i]);   // deg -> dinv
    float cnt=0.f; for(int i=tid;i<500;i+=256) cnt += msk[i];
    __syncthreads();
    red[tid]=cnt; __syncthreads();
    for(int s=128;s>0;s>>=1){ if(tid<s) red[tid]+=red[tid+s]; __syncthreads(); }
    const int len = iclamp((int)(red[0]+0.5f), 1, 500);
    __syncthreads();
    for(int i=tid;i<808;i+=256){ const int n=i>>3; agg1[i] = deg[n]*deg[n]*h1pre[i]; }
    __syncthreads();
    for(int i=tid;i<499*8;i+=256){
        const int e=i>>3, j=i&7, s=sk[e], d=sk[e+1];
        atomicAdd(&agg1[d*8+j], deg[s]*deg[d]*h1pre[s*8+j]);
    }
    __syncthreads();
    for(int i=tid;i<808;i+=256){ const int j=i&7; agg1[i] = fmaxf(agg1[i]+gcn_b1[j], 0.f); }
    __syncthreads();
    for(int i=tid;i<808;i+=256){ const int n=i>>3; agg2[i] = deg[n]*deg[n]*agg1[i]; }
    __syncthreads();
    for(int i=tid;i<499*8;i+=256){
        const int e=i>>3, j=i&7, s=sk[e], d=sk[e+1];
        atomicAdd(&agg2[d*8+j], deg[s]*deg[d]*agg1[s*8+j]);
    }
    const size_t prow = (size_t)(len-1)*500;
    float vmax = -1e30f;
    for(int i=tid;i<500;i+=256){ const float v = pos[prow+i]*msk[i]; coef[i]=v; vmax=fmaxf(vmax,v); }
    red[tid]=vmax; __syncthreads();           // also orders agg2 atomics
    for(int s=128;s>0;s>>=1){ if(tid<s) red[tid]=fmaxf(red[tid],red[tid+s]); __syncthreads(); }
    const float m = red[0]; __syncthreads();
    float lsum=0.f;
    for(int i=tid;i<500;i+=256){ const float e=__expf(coef[i]-m); coef[i]=e; lsum+=e; }
    red[tid]=lsum; __syncthreads();
    for(int s=128;s>0;s>>=1){ if(tid<s) red[tid]+=red[tid+s]; __syncthreads(); }
    const float inv = 1.f/red[0];
    __syncthreads();
    float v8[8]={0,0,0,0,0,0,0,0}; float ls=0.f;
    for(int i=tid;i<500;i+=256){
        const float ci = coef[i]*inv*msk[i];
        if(ci!=0.f){
            const int n=sk[i]; ls+=ci;
            #pragma unroll
            for(int j=0;j<8;j++) v8[j] += ci*agg2[n*8+j];
        }
    }
    #pragma unroll
    for(int j=0;j<8;j++) atomicAdd(&vec8[j], v8[j]);
    atomicAdd(&sS[0], ls);
    __syncthreads();
    {   // pooled row into LDS (red[]), same values the old global round-trip had
        const int o = tid;
        float acc = gcn_b2[o]*sS[0];
        #pragma unroll
        for(int j=0;j<8;j++) acc += vec8[j]*gcn_w2[o*8+j];
        red[o] = acc;
    }
    __syncthreads();
    {   // fused k_pooledproj: pooled_proj[b][o] = pooled[b] . wih_dg[o][0:256]
        const int o = tid;
        const float* w = wih_dg + (size_t)o*768;
        float acc=0.f;
        for(int k=0;k<256;k+=4){
            f32x4 wv = *(const f32x4*)&w[k];
            acc += red[k]*wv.x + red[k+1]*wv.y + red[k+2]*wv.z + red[k+3]*wv.w;
        }
        pooled_proj[b*256+o]=f2b(acc);
    }
}

// =============== RNN v6 (proven 366us): 16 waves, pre in MFMA C-init, ======
// scale folded into W, pointer strength-reduction. 8 blocks, wave = 16 cols.
__global__ __launch_bounds__(1024) void k_rnn(
    const u16* __restrict__ pre_dg, const u16* __restrict__ pre_hg,
    const float* __restrict__ whh_dg, const float* __restrict__ whh_hg,
    u16* __restrict__ hall_dg, u16* __restrict__ hall_hg)
{
    __shared__ u16 hc[2][8][4][16][8];    // 2 x 8KB, B-fragment chunk layout
    const int bid = blockIdx.x;
    const int rnn = bid>>2, grp = bid&3, rb = grp*16;
    const float* W   = rnn ? whh_hg : whh_dg;
    const u16*  pre  = rnn ? pre_hg : pre_dg;
    u16*        out  = rnn ? hall_hg : hall_dg;
    const int tid = threadIdx.x, wave = tid>>6, lane = tid&63;
    const int lm = lane&15, lg = lane>>4;
    const int cb = wave*16;

    // W fragments as A-operand (row = output col), register-resident, pre-scaled by C_TANH
    short8 wf[8];
    #pragma unroll
    for(int kk=0;kk<8;kk++)
        wf[kk] = ld8f_s(W + (size_t)(cb+lm)*256 + kk*32 + lg*8, C_TANH);

    for(int i=tid;i<2*8*4*16*8/2;i+=1024) ((unsigned*)hc)[i]=0;

    const size_t base = (size_t)(rb+lm)*256 + cb + lg*4;   // per-lane flat offset
    // LDS write slot (chunk layout): chunk = wave>>1, sub = (wave&1)*2+(lg>>1)
    const int wchunk = wave>>1, wsub = (wave&1)*2 + (lg>>1), wslot = (lg&1)*4;

    const u16* pp = pre + base;   // pre pointer, walks +16384 elems/step
    u16*       op = out + base;   // out pointer, walks +16384 elems/step
    uint2 pv = *(const uint2*)pp;
    pp += 16384;
    __syncthreads();

    auto stepf = [&](const u16 (&S)[8][4][16][8], u16 (&D)[8][4][16][8],
                     uint2 pvi, const u16* ppi, u16* opi)->uint2 {
        // C-init = pre (already scaled): saves the post-MFMA adds
        f32x4 a0, c0 = (f32x4){0.f,0.f,0.f,0.f};
        a0[0] = __uint_as_float(pvi.x << 16);
        a0[1] = __uint_as_float(pvi.x & 0xffff0000u);
        a0[2] = __uint_as_float(pvi.y << 16);
        a0[3] = __uint_as_float(pvi.y & 0xffff0000u);
        #pragma unroll
        for(int kk=0;kk<4;kk++){
            short8 hb = *(const short8*)&S[kk][lg][lm][0];
            a0 = __builtin_amdgcn_mfma_f32_16x16x32_bf16(wf[kk], hb, a0, 0,0,0);
        }
        #pragma unroll
        for(int kk=4;kk<8;kk++){
            short8 hb = *(const short8*)&S[kk][lg][lm][0];
            c0 = __builtin_amdgcn_mfma_f32_16x16x32_bf16(wf[kk], hb, c0, 0,0,0);
        }
        // prefetch next step's pre (t=500/501 reads stay inside the Gb allocation, never consumed)
        const uint2 pvn = *(const uint2*)ppi;
        float th[4];
        #pragma unroll
        for(int r=0;r<4;r++){
            const float x = a0[r] + c0[r];            // = c*(pre + W@h)
            const float e = fast_exp2(x);
            th[r] = fmaf(-2.f, __builtin_amdgcn_rcpf(e + 1.f), 1.f);
        }
        uint2 pk;
        asm("v_cvt_pk_bf16_f32 %0, %1, %2" : "=v"(pk.x) : "v"(th[0]), "v"(th[1]));
        asm("v_cvt_pk_bf16_f32 %0, %1, %2" : "=v"(pk.y) : "v"(th[2]), "v"(th[3]));
        *(uint2*)&D[wchunk][wsub][lm][wslot] = pk;
        *(uint2*)opi = pk;
        barrier_lds();      // LDS-visibility only: global loads/stores stay in flight
        return pvn;
    };

    for(int t=0;t<500;t+=2){
        pv = stepf(hc[0], hc[1], pv, pp, op);  pp += 16384; op += 16384;
        pv = stepf(hc[1], hc[0], pv, pp, op);  pp += 16384; op += 16384;
    }
}

// ====== theta = sigmoid(h_hg@w1^T + h_dg@w2^T + b1 + b2), dual-GEMM fused, bf16 out ======
// grid (250, 4), block 256.  M=32000, N=256, K=256.
__global__ __launch_bounds__(256) void k_theta(
    const u16* __restrict__ Ah, const u16* __restrict__ Ad,
    const float* __restrict__ w1, const float* __restrict__ w2,
    const float* __restrict__ b1, const float* __restrict__ b2,
    u16* __restrict__ theta)
{
    constexpr int BK=32;
    __shared__ u16 AsH[128][BK+8];
    __shared__ u16 AsD[128][BK+8];
    __shared__ u16 BsH[64][BK+8];
    __shared__ u16 BsD[64][BK+8];
    const int tid = threadIdx.x;
    const int bm = blockIdx.x*128, bn = blockIdx.y*64;
    const int wave = tid>>6, lane = tid&63, lm = lane&15, lg = lane>>4;
    const int wm = (wave>>1)*64, wn = (wave&1)*32;
    f32x4 acc[4][2];
    #pragma unroll
    for(int i=0;i<4;i++){ acc[i][0]=(f32x4){0.f,0.f,0.f,0.f}; acc[i][1]=(f32x4){0.f,0.f,0.f,0.f}; }

    const int arow0 = tid>>2, akc0 = (tid&3)*8;
    const int arow1 = arow0 + 64;
    for(int k0=0;k0<256;k0+=BK){
        *(short8*)&AsH[arow0][akc0] = ld8b(Ah + (size_t)(bm+arow0)*256 + k0+akc0);
        *(short8*)&AsH[arow1][akc0] = ld8b(Ah + (size_t)(bm+arow1)*256 + k0+akc0);
        *(short8*)&AsD[arow0][akc0] = ld8b(Ad + (size_t)(bm+arow0)*256 + k0+akc0);
        *(short8*)&AsD[arow1][akc0] = ld8b(Ad + (size_t)(bm+arow1)*256 + k0+akc0);
        *(short8*)&BsH[arow0][akc0] = ld8f(w1 + (size_t)(bn+arow0)*256 + k0+akc0);
        *(short8*)&BsD[arow0][akc0] = ld8f(w2 + (size_t)(bn+arow0)*256 + k0+akc0);
        __syncthreads();
        short8 afH[4], afD[4], bf1[2], bf2[2];
        #pragma unroll
        for(int mt=0;mt<4;mt++){
            afH[mt] = *(const short8*)&AsH[wm+mt*16+lm][lg*8];
            afD[mt] = *(const short8*)&AsD[wm+mt*16+lm][lg*8];
        }
        #pragma unroll
        for(int nt=0;nt<2;nt++){
            bf1[nt] = *(const short8*)&BsH[wn+nt*16+lm][lg*8];
            bf2[nt] = *(const short8*)&BsD[wn+nt*16+lm][lg*8];
        }
        #pragma unroll
        for(int nt=0;nt<2;nt++)
            #pragma unroll
            for(int mt=0;mt<4;mt++){
                acc[mt][nt] = __builtin_amdgcn_mfma_f32_16x16x32_bf16(afH[mt], bf1[nt], acc[mt][nt], 0,0,0);
                acc[mt][nt] = __builtin_amdgcn_mfma_f32_16x16x32_bf16(afD[mt], bf2[nt], acc[mt][nt], 0,0,0);
            }
        __syncthreads();
    }
    #pragma unroll
    for(int nt=0;nt<2;nt++){
        const int col = bn+wn+nt*16+lm;
        const float bb = b1[col]+b2[col];
        #pragma unroll
        for(int mt=0;mt<4;mt++){
            const int row0 = bm+wm+mt*16+lg*4;
            #pragma unroll
            for(int r=0;r<4;r++){
                const float x = acc[mt][nt][r] + bb;
                theta[(size_t)(row0+r)*256 + col] = f2b(1.f/(1.f+__expf(-x)));
            }
        }
    }
}

// =============== final gather: one wave per (b,t), three outputs ===============
__global__ __launch_bounds__(256) void k_out(
    const int* __restrict__ skill,
    const u16* __restrict__ hall_hg, const u16* __restrict__ hall_dg,
    const u16* __restrict__ theta,
    const float* __restrict__ fc_h_w, const float* __restrict__ fc_h_b,
    const float* __restrict__ fc_d_w, const float* __restrict__ fc_d_b,
    const float* __restrict__ fc_e_w, const float* __restrict__ fc_e_b,
    float* __restrict__ outp)
{
    const int tid=threadIdx.x, lane=tid&63;
    const int wid = blockIdx.x*4 + (tid>>6);        // 0..31935
    const int b = wid/499, t = wid - b*499;
    const int ns = skill[b*500 + t + 1];
    float o0=0.f,o1=0.f,o2=0.f,bh=0.f,bd=0.f,be=0.f;
    if(ns != 100){
        const int c = iclamp(ns, 0, 99);
        const size_t r = (size_t)t*64 + b;
        const int k = lane*4;
        short4v hh  = *(const short4v*)&hall_hg[r*256+k];
        short4v hd  = *(const short4v*)&hall_dg[r*256+k];
        short4v th  = *(const short4v*)&theta[r*256+k];
        f32x4 fh  = *(const f32x4*)&fc_h_w[(size_t)c*256+k];
        f32x4 fd  = *(const f32x4*)&fc_d_w[(size_t)c*256+k];
        f32x4 fe1 = *(const f32x4*)&fc_e_w[(size_t)c*512+k];
        f32x4 fe2 = *(const f32x4*)&fc_e_w[(size_t)c*512+256+k];
        #pragma unroll
        for(int j=0;j<4;j++){
            const float hhj=b2f((u16)hh[j]), hdj=b2f((u16)hd[j]), tj=b2f((u16)th[j]);
            o0 += hhj*fh[j];
            o1 += hdj*fd[j];
            o2 += tj*hhj*fe1[j] + (1.f-tj)*hdj*fe2[j];
        }
        #pragma unroll
        for(int off=32;off>0;off>>=1){
            o0 += __shfl_down(o0,off);
            o1 += __shfl_down(o1,off);
            o2 += __shfl_down(o2,off);
        }
        bh=fc_h_b[c]; bd=fc_d_b[c]; be=fc_e_b[c];
    }
    if(lane==0){
        outp[            b*499+t] = (ns==100)?0.f:(o0+bh);
        outp[31936     + b*499+t] = (ns==100)?0.f:(o1+bd);
        outp[2*31936   + b*499+t] = (ns==100)?0.f:(o2+be);
    }
}

// ================================= launch =================================
extern "C" void kernel_launch(void* const* d_in, const int* in_sizes, int n_in,
                              void* d_out, int out_size, void* d_ws, size_t ws_size,
                              hipStream_t stream)
{
    const int* student = (const int*)d_in[0];
    const int* skill   = (const int*)d_in[1];
    const int* answer  = (const int*)d_in[2];
    const float* G        = (const float*)d_in[3];
    const float* skill_emb= (const float*)d_in[4];
    const float* answer_emb=(const float*)d_in[5];
    const float* stu      = (const float*)d_in[6];
    const float* hg_w1    = (const float*)d_in[7];
    const float* hg_b1    = (const float*)d_in[8];
    const float* hg_w2    = (const float*)d_in[9];
    const float* hg_b2    = (const float*)d_in[10];
    const float* gcn_w1   = (const float*)d_in[11];
    const float* gcn_b1   = (const float*)d_in[12];
    const float* gcn_w2   = (const float*)d_in[13];
    const float* gcn_b2   = (const float*)d_in[14];
    const float* w1_w     = (const float*)d_in[15];
    const float* w1_b     = (const float*)d_in[16];
    const float* w2_w     = (const float*)d_in[17];
    const float* w2_b     = (const float*)d_in[18];
    const float* fc_d_w   = (const float*)d_in[19];
    const float* fc_d_b   = (const float*)d_in[20];
    const float* fc_h_w   = (const float*)d_in[21];
    const float* fc_h_b   = (const float*)d_in[22];
    const float* fc_e_w   = (const float*)d_in[23];
    const float* fc_e_b   = (const float*)d_in[24];
    const float* pos      = (const float*)d_in[25];
    const float* dg_wih   = (const float*)d_in[26];
    const float* dg_whh   = (const float*)d_in[27];
    const float* dg_bih   = (const float*)d_in[28];
    const float* dg_bhh   = (const float*)d_in[29];
    const float* hgr_wih  = (const float*)d_in[30];
    const float* hgr_whh  = (const float*)d_in[31];
    const float* hgr_bih  = (const float*)d_in[32];
    const float* hgr_bhh  = (const float*)d_in[33];

    char* ws = (char*)d_ws;
    size_t off = 0;
    auto nxt = [&](size_t bytes)->char*{
        char* r = ws + off;
        off += (bytes + 255) & ~(size_t)255;
        return r;
    };
    float* h1pre      = (float*)nxt(808*4);
    float* table_dg   = (float*)nxt(303*256*4);
    float* table_hg   = (float*)nxt(303*256*4);
    u16*   tmpT       = (u16*)  nxt((size_t)256*4096*2);
    u16*   hbuf       = (u16*)  nxt((size_t)4096*256*2);
    u16*   stu_proj   = (u16*)  nxt((size_t)4096*256*2);
    u16*   pooled_proj= (u16*)  nxt(64*256*2);
    int*   combo_t    = (int*)  nxt(32000*4);
    int*   sid_t      = (int*)  nxt(32000*4);
    unsigned* cnt     = (unsigned*)nxt(256);
    u16*   Gb         = (u16*)  nxt((size_t)4096*4096*2);   // 33.6 MB; dead after mega stage 4
    u16*   hall_dg    = (u16*)  nxt((size_t)32000*256*2);   // 16.4 MB
    u16*   hall_hg    = (u16*)  nxt((size_t)32000*256*2);   // 16.4 MB
    // overlays on Gb (Gb dead before mega stage 6 writes these):
    u16*   pre_dg     = Gb;
    u16*   pre_hg     = Gb + (size_t)32000*256;
    u16*   theta      = pre_dg;                              // pre_dg dead after k_rnn

    // fused prep (tables + idx + h1pre + G cvt + cnt reset), then GCN+proj
    k_prep<<<8931,256,0,stream>>>(skill_emb, answer_emb,
                                  dg_wih, dg_bih, dg_bhh,
                                  hgr_wih, hgr_bih, hgr_bhh,
                                  gcn_w1, skill, answer, student,
                                  G, Gb,
                                  table_dg, table_hg, h1pre, combo_t, sid_t, cnt);
    k_gcn<<<64,256,0,stream>>>(skill, answer, pos, h1pre, gcn_b1, gcn_w2, gcn_b2,
                               dg_wih, pooled_proj);

    // megakernel: 5 GEMM stages + k_pre, grid barriers between stages
    k_mega<<<256,256,0,stream>>>(stu, hg_w1, hg_b1, Gb, hg_w2, hg_b2, hgr_wih,
                                 tmpT, hbuf, stu_proj,
                                 combo_t, sid_t, table_dg, table_hg, pooled_proj,
                                 pre_dg, pre_hg, cnt);

    // recurrences
    k_rnn<<<8,1024,0,stream>>>(pre_dg, pre_hg, dg_whh, hgr_whh, hall_dg, hall_hg);

    // theta + outputs
    k_theta<<<dim3(250,4),256,0,stream>>>(hall_hg, hall_dg, w1_w, w2_w, w1_b, w2_b, theta);
    k_out<<<7984,256,0,stream>>>(skill, hall_hg, hall_dg, theta,
                                 fc_h_w, fc_h_b, fc_d_w, fc_d_b, fc_e_w, fc_e_b,
                                 (float*)d_out);
}

// Round 10
// 794.879 us; speedup vs baseline: 1.3453x; 1.3453x over previous
//
#include <hip/hip_runtime.h>
#include <cstdint>
#include <cstddef>

typedef unsigned short u16;
typedef __attribute__((ext_vector_type(8))) short short8;
typedef __attribute__((ext_vector_type(4))) short short4v;
typedef __attribute__((ext_vector_type(4))) float f32x4;

__device__ __forceinline__ float b2f(u16 u){ return __uint_as_float(((unsigned)u)<<16); }
__device__ __forceinline__ u16 f2b(float f){
    unsigned u = __float_as_uint(f);
    return (u16)((u + 0x7fffu + ((u>>16)&1u)) >> 16);
}
__device__ __forceinline__ int iclamp(int v, int lo, int hi){ return v<lo?lo:(v>hi?hi:v); }

// LDS-only barrier: no vmcnt(0) drain (global loads/stores stay in flight)
__device__ __forceinline__ void barrier_lds(){
    asm volatile("s_waitcnt lgkmcnt(0)\n\ts_barrier" ::: "memory");
}

__device__ __forceinline__ float fast_exp2(float x){
#if __has_builtin(__builtin_amdgcn_exp2f)
    return __builtin_amdgcn_exp2f(x);
#else
    return __expf(x * 0.6931471805599453f);
#endif
}

// 8-wide f32 -> bf16 fragment
__device__ __forceinline__ short8 ld8f(const float* p){
    f32x4 a = *(const f32x4*)p;
    f32x4 b = *(const f32x4*)(p+4);
    short8 r;
    #pragma unroll
    for(int j=0;j<4;j++){ r[j]=(short)f2b(a[j]); r[4+j]=(short)f2b(b[j]); }
    return r;
}
// scaled variant: round(s*W) — single bf16 rounding, same error class as round(W)
__device__ __forceinline__ short8 ld8f_s(const float* p, float s){
    f32x4 a = *(const f32x4*)p;
    f32x4 b = *(const f32x4*)(p+4);
    short8 r;
    #pragma unroll
    for(int j=0;j<4;j++){ r[j]=(short)f2b(a[j]*s); r[4+j]=(short)f2b(b[j]*s); }
    return r;
}
__device__ __forceinline__ short8 ld8b(const u16* p){ return *(const short8*)p; }

// tanh scale constant: 2*log2(e); tanh(v) = 1 - 2*rcp(exp2(c*v)+1)
#define C_TANH 2.8853900817779268f

// =============== G f32 -> bf16 (4096x4096) ===============
// One-shot cvt (100MB traffic) beats inlining f32 reads into the two K=4096 GEMMs
// (R6 measured +58us: 4 column-blocks re-read each A-strip -> 2x268MB f32 vs 2x134MB bf16).
__global__ __launch_bounds__(256) void k_cvt(const float* __restrict__ in, u16* __restrict__ outp){
    const size_t i = ((size_t)blockIdx.x*256 + threadIdx.x)*8;
    *(short8*)&outp[i] = ld8f(in + i);
}

// =============== 32x64-tile BT GEMM, single-barrier double-buffered LDS ===============
// C(MxN) = A(MxK) @ B(NxK)^T (+bias f32), bf16 out.
// grid (M/32, N/64), block 256 (4 waves as 2Mx2N, each 16x32 output).
// Rationale (R10): the old 64x64 tile gave grid=256 -> 1 block/CU -> 1 wave/SIMD,
// zero wave-level latency hiding on the dependent ds_read->MFMA path. 32-row tiles
// double the grid to 512 -> 2 blocks/CU, 2 waves/SIMD. Per-output math, K-order
// and f32 accumulation identical -> bit-identical results.
template<bool TRANSOUT, bool RELU, bool AF32, bool BF32>
__global__ __launch_bounds__(256) void gemm64(
    const void* __restrict__ A, const void* __restrict__ B,
    const float* __restrict__ bias, u16* __restrict__ C,
    int M, int N, int K, int ldb, int ldc)
{
    constexpr int BK=32;
    __shared__ u16 As[2][32][BK+8];
    __shared__ u16 Bs[2][64][BK+8];
    const int tid = threadIdx.x;
    const int bm = blockIdx.x*32, bn = blockIdx.y*64;
    const int wave = tid>>6, lane = tid&63, lm = lane&15, lg = lane>>4;
    const int wm = (wave>>1)*16, wn = (wave&1)*32;
    f32x4 acc[2];
    acc[0]=(f32x4){0.f,0.f,0.f,0.f}; acc[1]=(f32x4){0.f,0.f,0.f,0.f};

    const int srow = tid>>2, skc = (tid&3)*8;    // B: all 256 thr cover 64 rows; A: tid<128 cover 32
    auto lda8 = [&](int k)->short8{
        return AF32 ? ld8f((const float*)A + (size_t)(bm+srow)*K + k+skc)
                    : ld8b((const u16*)A + (size_t)(bm+srow)*K + k+skc);
    };
    auto ldb8v = [&](int k)->short8{
        return BF32 ? ld8f((const float*)B + (size_t)(bn+srow)*ldb + k+skc)
                    : ld8b((const u16*)B + (size_t)(bn+srow)*ldb + k+skc);
    };
    if(tid<128) *(short8*)&As[0][srow][skc] = lda8(0);
    *(short8*)&Bs[0][srow][skc] = ldb8v(0);
    barrier_lds();
    int p = 0;
    for(int k0=0;k0<K;k0+=BK){
        short8 a_n, b_n;
        const bool more = (k0+BK < K);
        if(more){ if(tid<128) a_n = lda8(k0+BK); b_n = ldb8v(k0+BK); }
        short8 af  = *(const short8*)&As[p][wm+lm][lg*8];
        short8 bf0 = *(const short8*)&Bs[p][wn+lm][lg*8];
        short8 bf1 = *(const short8*)&Bs[p][wn+16+lm][lg*8];
        if(more){
            if(tid<128) *(short8*)&As[p^1][srow][skc] = a_n;
            *(short8*)&Bs[p^1][srow][skc] = b_n;
        }
        acc[0] = __builtin_amdgcn_mfma_f32_16x16x32_bf16(af, bf0, acc[0], 0,0,0);
        acc[1] = __builtin_amdgcn_mfma_f32_16x16x32_bf16(af, bf1, acc[1], 0,0,0);
        barrier_lds();
        p ^= 1;
    }
    #pragma unroll
    for(int nt=0;nt<2;nt++){
        const int col = bn+wn+nt*16+lm;
        const float bv = bias ? bias[col] : 0.f;
        const int row0 = bm+wm+lg*4;
        #pragma unroll
        for(int r=0;r<4;r++){
            const int row = row0+r;
            float v = acc[nt][r] + bv;
            if(RELU) v = fmaxf(v, 0.f);
            const size_t idx = TRANSOUT ? ((size_t)col*ldc + row) : ((size_t)row*ldc + col);
            C[idx] = f2b(v);
        }
    }
}

// ====== k_prep: fused independent prep — tables (606 blk) + idx (125 blk) + h1pre (8 blk) ======
__global__ __launch_bounds__(256) void k_prep(
    const float* __restrict__ skill_emb, const float* __restrict__ answer_emb,
    const float* __restrict__ wih_dg, const float* __restrict__ bih_dg, const float* __restrict__ bhh_dg,
    const float* __restrict__ wih_hg, const float* __restrict__ bih_hg, const float* __restrict__ bhh_hg,
    const float* __restrict__ gcn_w1,
    const int* __restrict__ skill, const int* __restrict__ answer, const int* __restrict__ student,
    float* __restrict__ table_dg, float* __restrict__ table_hg,
    float* __restrict__ h1pre, int* __restrict__ combo_t, int* __restrict__ sid_t)
{
    const int bid = blockIdx.x, tid = threadIdx.x;
    if(bid < 606){
        // table part: table[combo] = x(skill,answer) @ Wih[:,256:768]^T + bih + bhh
        const int which = (bid >= 303) ? 1 : 0;
        const int combo = bid - which*303;
        const float* wih = which ? wih_hg : wih_dg;
        const float* bih = which ? bih_hg : bih_dg;
        const float* bhh = which ? bhh_hg : bhh_dg;
        float* table     = which ? table_hg : table_dg;
        const int sid = combo/3, ans = combo - sid*3;
        __shared__ float sf[256], sg[256];
        sf[tid] = (ans==1) ? skill_emb[(size_t)sid*256+tid] : answer_emb[(size_t)ans*256+tid];
        sg[tid] = (ans==1) ? answer_emb[(size_t)ans*256+tid] : skill_emb[(size_t)sid*256+tid];
        __syncthreads();
        const int o = tid;
        float acc = bih[o] + bhh[o];
        const float* w = wih + (size_t)o*768;
        for(int k=0;k<256;k+=4){
            f32x4 w1v = *(const f32x4*)&w[256+k];
            f32x4 w2v = *(const f32x4*)&w[512+k];
            acc += sf[k]*w1v.x + sf[k+1]*w1v.y + sf[k+2]*w1v.z + sf[k+3]*w1v.w;
            acc += sg[k]*w2v.x + sg[k+1]*w2v.y + sg[k+2]*w2v.z + sg[k+3]*w2v.w;
        }
        table[(size_t)combo*256 + o] = acc;
    } else if(bid < 731){
        // idx part: combo/sid arrays, t-major, clamped
        const int i = (bid-606)*256 + tid;
        if(i>=32000) return;
        const int t = i>>6, b = i&63;
        const int sk = iclamp(skill[b*500+t], 0, 100);
        const int an = iclamp(answer[b*500+t], 0, 2);
        const int sd = iclamp(student[b*500+t]-1, 0, 4095);
        combo_t[i] = sk*3+an;
        sid_t[i]   = sd;
    } else {
        // h1pre part: skill_emb @ gcn_w1^T (101x8)
        if(tid >= 101) return;
        const int idx = (bid-731)*101 + tid;
        if(idx>=808) return;
        const int n=idx>>3, j=idx&7;
        const float* x = skill_emb + n*256;
        const float* w = gcn_w1 + j*256;
        float acc=0.f;
        for(int k=0;k<256;k+=4){
            f32x4 a = *(const f32x4*)&x[k];
            f32x4 b = *(const f32x4*)&w[k];
            acc += a.x*b.x + a.y*b.y + a.z*b.z + a.w*b.w;
        }
        h1pre[idx]=acc;
    }
}

// =============== per-batch skill GCN + softmax pooling + fused dg_wih projection ======
// -> pooled_proj (bf16 64x256). pooled row never leaves the block (LDS red[]).
__global__ __launch_bounds__(256) void k_gcn(
    const int* __restrict__ skill, const int* __restrict__ answer,
    const float* __restrict__ pos, const float* __restrict__ h1pre,
    const float* __restrict__ gcn_b1, const float* __restrict__ gcn_w2, const float* __restrict__ gcn_b2,
    const float* __restrict__ wih_dg,
    u16* __restrict__ pooled_proj)
{
    const int b = blockIdx.x, tid = threadIdx.x;
    __shared__ int   sk[500];
    __shared__ float msk[500];
    __shared__ float coef[500];
    __shared__ float deg[101];
    __shared__ float agg1[101*8];
    __shared__ float agg2[101*8];
    __shared__ float red[256];
    __shared__ float vec8[8];
    __shared__ float sS[1];

    for(int i=tid;i<500;i+=256){
        sk[i]=iclamp(skill[b*500+i],0,100);
        msk[i] = (answer[b*500+i]!=2)?1.f:0.f;
    }
    for(int i=tid;i<101;i+=256) deg[i]=1.f;           // self loop
    if(tid<8)  vec8[tid]=0.f;
    if(tid==8) sS[0]=0.f;
    __syncthreads();
    for(int e=tid;e<499;e+=256) atomicAdd(&deg[sk[e+1]], 1.f);
    __syncthreads();
    for(int i=tid;i<101;i+=256) deg[i] = rsqrtf(deg[i]);   // deg -> dinv
    float cnt=0.f; for(int i=tid;i<500;i+=256) cnt += msk[i];
    __syncthreads();
    red[tid]=cnt; __syncthreads();
    for(int s=128;s>0;s>>=1){ if(tid<s) red[tid]+=red[tid+s]; __syncthreads(); }
    const int len = iclamp((int)(red[0]+0.5f), 1, 500);
    __syncthreads();
    for(int i=tid;i<808;i+=256){ const int n=i>>3; agg1[i] = deg[n]*deg[n]*h1pre[i]; }
    __syncthreads();
    for(int i=tid;i<499*8;i+=256){
        const int e=i>>3, j=i&7, s=sk[e], d=sk[e+1];
        atomicAdd(&agg1[d*8+j], deg[s]*deg[d]*h1pre[s*8+j]);
    }
    __syncthreads();
    for(int i=tid;i<808;i+=256){ const int j=i&7; agg1[i] = fmaxf(agg1[i]+gcn_b1[j], 0.f); }
    __syncthreads();
    for(int i=tid;i<808;i+=256){ const int n=i>>3; agg2[i] = deg[n]*deg[n]*agg1[i]; }
    __syncthreads();
    for(int i=tid;i<499*8;i+=256){
        const int e=i>>3, j=i&7, s=sk[e], d=sk[e+1];
        atomicAdd(&agg2[d*8+j], deg[s]*deg[d]*agg1[s*8+j]);
    }
    const size_t prow = (size_t)(len-1)*500;
    float vmax = -1e30f;
    for(int i=tid;i<500;i+=256){ const float v = pos[prow+i]*msk[i]; coef[i]=v; vmax=fmaxf(vmax,v); }
    red[tid]=vmax; __syncthreads();           // also orders agg2 atomics
    for(int s=128;s>0;s>>=1){ if(tid<s) red[tid]=fmaxf(red[tid],red[tid+s]); __syncthreads(); }
    const float m = red[0]; __syncthreads();
    float lsum=0.f;
    for(int i=tid;i<500;i+=256){ const float e=__expf(coef[i]-m); coef[i]=e; lsum+=e; }
    red[tid]=lsum; __syncthreads();
    for(int s=128;s>0;s>>=1){ if(tid<s) red[tid]+=red[tid+s]; __syncthreads(); }
    const float inv = 1.f/red[0];
    __syncthreads();
    float v8[8]={0,0,0,0,0,0,0,0}; float ls=0.f;
    for(int i=tid;i<500;i+=256){
        const float ci = coef[i]*inv*msk[i];
        if(ci!=0.f){
            const int n=sk[i]; ls+=ci;
            #pragma unroll
            for(int j=0;j<8;j++) v8[j] += ci*agg2[n*8+j];
        }
    }
    #pragma unroll
    for(int j=0;j<8;j++) atomicAdd(&vec8[j], v8[j]);
    atomicAdd(&sS[0], ls);
    __syncthreads();
    {   // pooled row into LDS (red[]), same values the old global round-trip had
        const int o = tid;
        float acc = gcn_b2[o]*sS[0];
        #pragma unroll
        for(int j=0;j<8;j++) acc += vec8[j]*gcn_w2[o*8+j];
        red[o] = acc;
    }
    __syncthreads();
    {   // fused k_pooledproj: pooled_proj[b][o] = pooled[b] . wih_dg[o][0:256]
        const int o = tid;
        const float* w = wih_dg + (size_t)o*768;
        float acc=0.f;
        for(int k=0;k<256;k+=4){
            f32x4 wv = *(const f32x4*)&w[k];
            acc += red[k]*wv.x + red[k+1]*wv.y + red[k+2]*wv.z + red[k+3]*wv.w;
        }
        pooled_proj[b*256+o]=f2b(acc);
    }
}

// ====== k_pre: pre[rnn][t][b][c] = (table[combo] + proj) * C_TANH  (bf16, t-major) ======
// Pre-scaled by 2*log2(e) so k_rnn's tanh needs no multiplies (W is scaled likewise).
// grid (500, 2, 4), block 256.
__global__ __launch_bounds__(256) void k_pre(
    const int* __restrict__ combo_t, const int* __restrict__ sid_t,
    const float* __restrict__ table_dg, const float* __restrict__ table_hg,
    const u16* __restrict__ pooled_proj, const u16* __restrict__ stu_proj,
    u16* __restrict__ pre_dg, u16* __restrict__ pre_hg)
{
    const int t = blockIdx.x, rnn = blockIdx.y, c = threadIdx.x;
    const int b0 = blockIdx.z*16;
    const float* tab = rnn ? table_hg : table_dg;
    u16* outp = rnn ? pre_hg : pre_dg;
    for(int b=b0;b<b0+16;b++){
        const int cmb = combo_t[t*64+b];
        const u16* prow = rnn ? (stu_proj + (size_t)sid_t[t*64+b]*256)
                              : (pooled_proj + (size_t)b*256);
        const float v = (tab[(size_t)cmb*256 + c] + b2f(prow[c])) * C_TANH;
        outp[((size_t)t*64+b)*256 + c] = f2b(v);
    }
}

// =============== RNN v6 (proven 366us): 16 waves, pre in MFMA C-init, ======
// scale folded into W, pointer strength-reduction. 8 blocks, wave = 16 cols.
__global__ __launch_bounds__(1024) void k_rnn(
    const u16* __restrict__ pre_dg, const u16* __restrict__ pre_hg,
    const float* __restrict__ whh_dg, const float* __restrict__ whh_hg,
    u16* __restrict__ hall_dg, u16* __restrict__ hall_hg)
{
    __shared__ u16 hc[2][8][4][16][8];    // 2 x 8KB, B-fragment chunk layout
    const int bid = blockIdx.x;
    const int rnn = bid>>2, grp = bid&3, rb = grp*16;
    const float* W   = rnn ? whh_hg : whh_dg;
    const u16*  pre  = rnn ? pre_hg : pre_dg;
    u16*        out  = rnn ? hall_hg : hall_dg;
    const int tid = threadIdx.x, wave = tid>>6, lane = tid&63;
    const int lm = lane&15, lg = lane>>4;
    const int cb = wave*16;

    // W fragments as A-operand (row = output col), register-resident, pre-scaled by C_TANH
    short8 wf[8];
    #pragma unroll
    for(int kk=0;kk<8;kk++)
        wf[kk] = ld8f_s(W + (size_t)(cb+lm)*256 + kk*32 + lg*8, C_TANH);

    for(int i=tid;i<2*8*4*16*8/2;i+=1024) ((unsigned*)hc)[i]=0;

    const size_t base = (size_t)(rb+lm)*256 + cb + lg*4;   // per-lane flat offset
    // LDS write slot (chunk layout): chunk = wave>>1, sub = (wave&1)*2+(lg>>1)
    const int wchunk = wave>>1, wsub = (wave&1)*2 + (lg>>1), wslot = (lg&1)*4;

    const u16* pp = pre + base;   // pre pointer, walks +16384 elems/step
    u16*       op = out + base;   // out pointer, walks +16384 elems/step
    uint2 pv = *(const uint2*)pp;
    pp += 16384;
    __syncthreads();

    auto stepf = [&](const u16 (&S)[8][4][16][8], u16 (&D)[8][4][16][8],
                     uint2 pvi, const u16* ppi, u16* opi)->uint2 {
        // C-init = pre (already scaled): saves the post-MFMA adds
        f32x4 a0, c0 = (f32x4){0.f,0.f,0.f,0.f};
        a0[0] = __uint_as_float(pvi.x << 16);
        a0[1] = __uint_as_float(pvi.x & 0xffff0000u);
        a0[2] = __uint_as_float(pvi.y << 16);
        a0[3] = __uint_as_float(pvi.y & 0xffff0000u);
        #pragma unroll
        for(int kk=0;kk<4;kk++){
            short8 hb = *(const short8*)&S[kk][lg][lm][0];
            a0 = __builtin_amdgcn_mfma_f32_16x16x32_bf16(wf[kk], hb, a0, 0,0,0);
        }
        #pragma unroll
        for(int kk=4;kk<8;kk++){
            short8 hb = *(const short8*)&S[kk][lg][lm][0];
            c0 = __builtin_amdgcn_mfma_f32_16x16x32_bf16(wf[kk], hb, c0, 0,0,0);
        }
        // prefetch next step's pre (t=500/501 reads stay inside the Gb allocation, never consumed)
        const uint2 pvn = *(const uint2*)ppi;
        float th[4];
        #pragma unroll
        for(int r=0;r<4;r++){
            const float x = a0[r] + c0[r];            // = c*(pre + W@h)
            const float e = fast_exp2(x);
            th[r] = fmaf(-2.f, __builtin_amdgcn_rcpf(e + 1.f), 1.f);
        }
        uint2 pk;
        asm("v_cvt_pk_bf16_f32 %0, %1, %2" : "=v"(pk.x) : "v"(th[0]), "v"(th[1]));
        asm("v_cvt_pk_bf16_f32 %0, %1, %2" : "=v"(pk.y) : "v"(th[2]), "v"(th[3]));
        *(uint2*)&D[wchunk][wsub][lm][wslot] = pk;
        *(uint2*)opi = pk;
        barrier_lds();      // LDS-visibility only: global loads/stores stay in flight
        return pvn;
    };

    for(int t=0;t<500;t+=2){
        pv = stepf(hc[0], hc[1], pv, pp, op);  pp += 16384; op += 16384;
        pv = stepf(hc[1], hc[0], pv, pp, op);  pp += 16384; op += 16384;
    }
}

// ====== theta = sigmoid(h_hg@w1^T + h_dg@w2^T + b1 + b2), dual-GEMM fused, bf16 out ======
// grid (250, 4), block 256.  M=32000, N=256, K=256.
__global__ __launch_bounds__(256) void k_theta(
    const u16* __restrict__ Ah, const u16* __restrict__ Ad,
    const float* __restrict__ w1, const float* __restrict__ w2,
    const float* __restrict__ b1, const float* __restrict__ b2,
    u16* __restrict__ theta)
{
    constexpr int BK=32;
    __shared__ u16 AsH[128][BK+8];
    __shared__ u16 AsD[128][BK+8];
    __shared__ u16 BsH[64][BK+8];
    __shared__ u16 BsD[64][BK+8];
    const int tid = threadIdx.x;
    const int bm = blockIdx.x*128, bn = blockIdx.y*64;
    const int wave = tid>>6, lane = tid&63, lm = lane&15, lg = lane>>4;
    const int wm = (wave>>1)*64, wn = (wave&1)*32;
    f32x4 acc[4][2];
    #pragma unroll
    for(int i=0;i<4;i++){ acc[i][0]=(f32x4){0.f,0.f,0.f,0.f}; acc[i][1]=(f32x4){0.f,0.f,0.f,0.f}; }

    const int arow0 = tid>>2, akc0 = (tid&3)*8;
    const int arow1 = arow0 + 64;
    for(int k0=0;k0<256;k0+=BK){
        *(short8*)&AsH[arow0][akc0] = ld8b(Ah + (size_t)(bm+arow0)*256 + k0+akc0);
        *(short8*)&AsH[arow1][akc0] = ld8b(Ah + (size_t)(bm+arow1)*256 + k0+akc0);
        *(short8*)&AsD[arow0][akc0] = ld8b(Ad + (size_t)(bm+arow0)*256 + k0+akc0);
        *(short8*)&AsD[arow1][akc0] = ld8b(Ad + (size_t)(bm+arow1)*256 + k0+akc0);
        *(short8*)&BsH[arow0][akc0] = ld8f(w1 + (size_t)(bn+arow0)*256 + k0+akc0);
        *(short8*)&BsD[arow0][akc0] = ld8f(w2 + (size_t)(bn+arow0)*256 + k0+akc0);
        __syncthreads();
        short8 afH[4], afD[4], bf1[2], bf2[2];
        #pragma unroll
        for(int mt=0;mt<4;mt++){
            afH[mt] = *(const short8*)&AsH[wm+mt*16+lm][lg*8];
            afD[mt] = *(const short8*)&AsD[wm+mt*16+lm][lg*8];
        }
        #pragma unroll
        for(int nt=0;nt<2;nt++){
            bf1[nt] = *(const short8*)&BsH[wn+nt*16+lm][lg*8];
            bf2[nt] = *(const short8*)&BsD[wn+nt*16+lm][lg*8];
        }
        #pragma unroll
        for(int nt=0;nt<2;nt++)
            #pragma unroll
            for(int mt=0;mt<4;mt++){
                acc[mt][nt] = __builtin_amdgcn_mfma_f32_16x16x32_bf16(afH[mt], bf1[nt], acc[mt][nt], 0,0,0);
                acc[mt][nt] = __builtin_amdgcn_mfma_f32_16x16x32_bf16(afD[mt], bf2[nt], acc[mt][nt], 0,0,0);
            }
        __syncthreads();
    }
    #pragma unroll
    for(int nt=0;nt<2;nt++){
        const int col = bn+wn+nt*16+lm;
        const float bb = b1[col]+b2[col];
        #pragma unroll
        for(int mt=0;mt<4;mt++){
            const int row0 = bm+wm+mt*16+lg*4;
            #pragma unroll
            for(int r=0;r<4;r++){
                const float x = acc[mt][nt][r] + bb;
                theta[(size_t)(row0+r)*256 + col] = f2b(1.f/(1.f+__expf(-x)));
            }
        }
    }
}

// =============== final gather: one wave per (b,t), three outputs ===============
__global__ __launch_bounds__(256) void k_out(
    const int* __restrict__ skill,
    const u16* __restrict__ hall_hg, const u16* __restrict__ hall_dg,
    const u16* __restrict__ theta,
    const float* __restrict__ fc_h_w, const float* __restrict__ fc_h_b,
    const float* __restrict__ fc_d_w, const float* __restrict__ fc_d_b,
    const float* __restrict__ fc_e_w, const float* __restrict__ fc_e_b,
    float* __restrict__ outp)
{
    const int tid=threadIdx.x, lane=tid&63;
    const int wid = blockIdx.x*4 + (tid>>6);        // 0..31935
    const int b = wid/499, t = wid - b*499;
    const int ns = skill[b*500 + t + 1];
    float o0=0.f,o1=0.f,o2=0.f,bh=0.f,bd=0.f,be=0.f;
    if(ns != 100){
        const int c = iclamp(ns, 0, 99);
        const size_t r = (size_t)t*64 + b;
        const int k = lane*4;
        short4v hh  = *(const short4v*)&hall_hg[r*256+k];
        short4v hd  = *(const short4v*)&hall_dg[r*256+k];
        short4v th  = *(const short4v*)&theta[r*256+k];
        f32x4 fh  = *(const f32x4*)&fc_h_w[(size_t)c*256+k];
        f32x4 fd  = *(const f32x4*)&fc_d_w[(size_t)c*256+k];
        f32x4 fe1 = *(const f32x4*)&fc_e_w[(size_t)c*512+k];
        f32x4 fe2 = *(const f32x4*)&fc_e_w[(size_t)c*512+256+k];
        #pragma unroll
        for(int j=0;j<4;j++){
            const float hhj=b2f((u16)hh[j]), hdj=b2f((u16)hd[j]), tj=b2f((u16)th[j]);
            o0 += hhj*fh[j];
            o1 += hdj*fd[j];
            o2 += tj*hhj*fe1[j] + (1.f-tj)*hdj*fe2[j];
        }
        #pragma unroll
        for(int off=32;off>0;off>>=1){
            o0 += __shfl_down(o0,off);
            o1 += __shfl_down(o1,off);
            o2 += __shfl_down(o2,off);
        }
        bh=fc_h_b[c]; bd=fc_d_b[c]; be=fc_e_b[c];
    }
    if(lane==0){
        outp[            b*499+t] = (ns==100)?0.f:(o0+bh);
        outp[31936     + b*499+t] = (ns==100)?0.f:(o1+bd);
        outp[2*31936   + b*499+t] = (ns==100)?0.f:(o2+be);
    }
}

// ================================= launch =================================
extern "C" void kernel_launch(void* const* d_in, const int* in_sizes, int n_in,
                              void* d_out, int out_size, void* d_ws, size_t ws_size,
                              hipStream_t stream)
{
    const int* student = (const int*)d_in[0];
    const int* skill   = (const int*)d_in[1];
    const int* answer  = (const int*)d_in[2];
    const float* G        = (const float*)d_in[3];
    const float* skill_emb= (const float*)d_in[4];
    const float* answer_emb=(const float*)d_in[5];
    const float* stu      = (const float*)d_in[6];
    const float* hg_w1    = (const float*)d_in[7];
    const float* hg_b1    = (const float*)d_in[8];
    const float* hg_w2    = (const float*)d_in[9];
    const float* hg_b2    = (const float*)d_in[10];
    const float* gcn_w1   = (const float*)d_in[11];
    const float* gcn_b1   = (const float*)d_in[12];
    const float* gcn_w2   = (const float*)d_in[13];
    const float* gcn_b2   = (const float*)d_in[14];
    const float* w1_w     = (const float*)d_in[15];
    const float* w1_b     = (const float*)d_in[16];
    const float* w2_w     = (const float*)d_in[17];
    const float* w2_b     = (const float*)d_in[18];
    const float* fc_d_w   = (const float*)d_in[19];
    const float* fc_d_b   = (const float*)d_in[20];
    const float* fc_h_w   = (const float*)d_in[21];
    const float* fc_h_b   = (const float*)d_in[22];
    const float* fc_e_w   = (const float*)d_in[23];
    const float* fc_e_b   = (const float*)d_in[24];
    const float* pos      = (const float*)d_in[25];
    const float* dg_wih   = (const float*)d_in[26];
    const float* dg_whh   = (const float*)d_in[27];
    const float* dg_bih   = (const float*)d_in[28];
    const float* dg_bhh   = (const float*)d_in[29];
    const float* hgr_wih  = (const float*)d_in[30];
    const float* hgr_whh  = (const float*)d_in[31];
    const float* hgr_bih  = (const float*)d_in[32];
    const float* hgr_bhh  = (const float*)d_in[33];

    char* ws = (char*)d_ws;
    size_t off = 0;
    auto nxt = [&](size_t bytes)->char*{
        char* r = ws + off;
        off += (bytes + 255) & ~(size_t)255;
        return r;
    };
    float* h1pre      = (float*)nxt(808*4);
    float* table_dg   = (float*)nxt(303*256*4);
    float* table_hg   = (float*)nxt(303*256*4);
    u16*   tmpT       = (u16*)  nxt((size_t)256*4096*2);
    u16*   hbuf       = (u16*)  nxt((size_t)4096*256*2);
    u16*   stu_proj   = (u16*)  nxt((size_t)4096*256*2);
    u16*   pooled_proj= (u16*)  nxt(64*256*2);
    int*   combo_t    = (int*)  nxt(32000*4);
    int*   sid_t      = (int*)  nxt(32000*4);
    u16*   Gb         = (u16*)  nxt((size_t)4096*4096*2);   // 33.6 MB; dead after gemm#4
    u16*   hall_dg    = (u16*)  nxt((size_t)32000*256*2);   // 16.4 MB
    u16*   hall_hg    = (u16*)  nxt((size_t)32000*256*2);   // 16.4 MB
    // overlays on Gb (Gb dead before k_pre writes these):
    u16*   pre_dg     = Gb;
    u16*   pre_hg     = Gb + (size_t)32000*256;
    u16*   theta      = pre_dg;                              // pre_dg dead after k_rnn

    // fused prep (tables + idx + h1pre), GCN+proj, G cvt
    k_prep<<<739,256,0,stream>>>(skill_emb, answer_emb,
                                 dg_wih, dg_bih, dg_bhh,
                                 hgr_wih, hgr_bih, hgr_bhh,
                                 gcn_w1, skill, answer, student,
                                 table_dg, table_hg, h1pre, combo_t, sid_t);
    k_gcn<<<64,256,0,stream>>>(skill, answer, pos, h1pre, gcn_b1, gcn_w2, gcn_b2,
                               dg_wih, pooled_proj);
    k_cvt<<<8192,256,0,stream>>>(G, Gb);

    // student GCN chain (32x64-tile dbuf gemm, 512 blocks = 2 blocks/CU)
    gemm64<true ,false,true ,true ><<<dim3(128,4),256,0,stream>>>(stu,  hg_w1, hg_b1, tmpT, 4096,256,256,  256, 4096);
    gemm64<false,true ,false,false><<<dim3(128,4),256,0,stream>>>(Gb,   tmpT,  nullptr, hbuf, 4096,256,4096, 4096, 256);
    gemm64<true ,false,false,true ><<<dim3(128,4),256,0,stream>>>(hbuf, hg_w2, hg_b2, tmpT, 4096,256,256,  256, 4096);
    gemm64<false,false,false,false><<<dim3(128,4),256,0,stream>>>(Gb,   tmpT,  nullptr, hbuf, 4096,256,4096, 4096, 256);
    gemm64<false,false,false,true ><<<dim3(128,4),256,0,stream>>>(hbuf, hgr_wih, nullptr, stu_proj, 4096,256,256, 768, 256);

    // fused pre-activation array (t-major bf16, pre-scaled by 2*log2e) — overwrites Gb (dead)
    k_pre<<<dim3(500,2,4),256,0,stream>>>(combo_t, sid_t, table_dg, table_hg,
                                          pooled_proj, stu_proj, pre_dg, pre_hg);

    // recurrences
    k_rnn<<<8,1024,0,stream>>>(pre_dg, pre_hg, dg_whh, hgr_whh, hall_dg, hall_hg);

    // theta + outputs
    k_theta<<<dim3(250,4),256,0,stream>>>(hall_hg, hall_dg, w1_w, w2_w, w1_b, w2_b, theta);
    k_out<<<7984,256,0,stream>>>(skill, hall_hg, hall_dg, theta,
                                 fc_h_w, fc_h_b, fc_d_w, fc_d_b, fc_e_w, fc_e_b,
                                 (float*)d_out);
}

// Round 11
// 770.833 us; speedup vs baseline: 1.3873x; 1.0312x over previous
//
#include <hip/hip_runtime.h>
#include <cstdint>
#include <cstddef>

typedef unsigned short u16;
typedef __attribute__((ext_vector_type(8))) short short8;
typedef __attribute__((ext_vector_type(4))) short short4v;
typedef __attribute__((ext_vector_type(4))) float f32x4;

__device__ __forceinline__ float b2f(u16 u){ return __uint_as_float(((unsigned)u)<<16); }
__device__ __forceinline__ u16 f2b(float f){
    unsigned u = __float_as_uint(f);
    return (u16)((u + 0x7fffu + ((u>>16)&1u)) >> 16);
}
__device__ __forceinline__ int iclamp(int v, int lo, int hi){ return v<lo?lo:(v>hi?hi:v); }

// LDS-only barrier: no vmcnt(0) drain (global loads/stores stay in flight)
__device__ __forceinline__ void barrier_lds(){
    asm volatile("s_waitcnt lgkmcnt(0)\n\ts_barrier" ::: "memory");
}

__device__ __forceinline__ float fast_exp2(float x){
#if __has_builtin(__builtin_amdgcn_exp2f)
    return __builtin_amdgcn_exp2f(x);
#else
    return __expf(x * 0.6931471805599453f);
#endif
}

// 8-wide f32 -> bf16 fragment
__device__ __forceinline__ short8 ld8f(const float* p){
    f32x4 a = *(const f32x4*)p;
    f32x4 b = *(const f32x4*)(p+4);
    short8 r;
    #pragma unroll
    for(int j=0;j<4;j++){ r[j]=(short)f2b(a[j]); r[4+j]=(short)f2b(b[j]); }
    return r;
}
// scaled variant: round(s*W) — single bf16 rounding, same error class as round(W)
__device__ __forceinline__ short8 ld8f_s(const float* p, float s){
    f32x4 a = *(const f32x4*)p;
    f32x4 b = *(const f32x4*)(p+4);
    short8 r;
    #pragma unroll
    for(int j=0;j<4;j++){ r[j]=(short)f2b(a[j]*s); r[4+j]=(short)f2b(b[j]*s); }
    return r;
}
__device__ __forceinline__ short8 ld8b(const u16* p){ return *(const short8*)p; }

// tanh scale constant: 2*log2(e); tanh(v) = 1 - 2*rcp(exp2(c*v)+1)
#define C_TANH 2.8853900817779268f

// =============== 64x64-tile BT GEMM body, single-barrier double-buffered LDS ===============
// C(MxN) = A(MxK) @ B(NxK)^T (+bias f32), bf16 out.  bx in [0,M/64), by in [0,N/64).
// (R7's proven version — 786us config; shared by standalone kernel and k_misc.)
template<bool TRANSOUT, bool RELU, bool AF32, bool BF32>
__device__ __forceinline__ void gemm_body(
    const void* __restrict__ A, const void* __restrict__ B,
    const float* __restrict__ bias, u16* __restrict__ C,
    int M, int N, int K, int ldb, int ldc, int bx, int by,
    u16 (&As)[2][64][40], u16 (&Bs)[2][64][40])
{
    constexpr int BK=32;
    const int tid = threadIdx.x;
    const int bm = bx*64, bn = by*64;
    const int wave = tid>>6, lane = tid&63, lm = lane&15, lg = lane>>4;
    const int wm = (wave>>1)*32, wn = (wave&1)*32;
    f32x4 acc[2][2];
    #pragma unroll
    for(int i=0;i<2;i++){ acc[i][0]=(f32x4){0.f,0.f,0.f,0.f}; acc[i][1]=(f32x4){0.f,0.f,0.f,0.f}; }

    const int arow = tid>>2, akc = (tid&3)*8;
    auto lda8 = [&](int k)->short8{
        return AF32 ? ld8f((const float*)A + (size_t)(bm+arow)*K + k+akc)
                    : ld8b((const u16*)A + (size_t)(bm+arow)*K + k+akc);
    };
    auto ldb8v = [&](int k)->short8{
        return BF32 ? ld8f((const float*)B + (size_t)(bn+arow)*ldb + k+akc)
                    : ld8b((const u16*)B + (size_t)(bn+arow)*ldb + k+akc);
    };
    *(short8*)&As[0][arow][akc] = lda8(0);
    *(short8*)&Bs[0][arow][akc] = ldb8v(0);
    barrier_lds();
    int p = 0;
    for(int k0=0;k0<K;k0+=BK){
        short8 a_n, b_n;
        const bool more = (k0+BK < K);
        if(more){ a_n = lda8(k0+BK); b_n = ldb8v(k0+BK); }
        short8 af[2], bfg[2];
        #pragma unroll
        for(int mt=0;mt<2;mt++) af[mt]  = *(const short8*)&As[p][wm+mt*16+lm][lg*8];
        #pragma unroll
        for(int nt=0;nt<2;nt++) bfg[nt] = *(const short8*)&Bs[p][wn+nt*16+lm][lg*8];
        #pragma unroll
        for(int nt=0;nt<2;nt++)
            #pragma unroll
            for(int mt=0;mt<2;mt++)
                acc[mt][nt] = __builtin_amdgcn_mfma_f32_16x16x32_bf16(af[mt], bfg[nt], acc[mt][nt], 0,0,0);
        if(more){
            *(short8*)&As[p^1][arow][akc] = a_n;
            *(short8*)&Bs[p^1][arow][akc] = b_n;
        }
        barrier_lds();
        p ^= 1;
    }
    #pragma unroll
    for(int nt=0;nt<2;nt++){
        const int col = bn+wn+nt*16+lm;
        const float bv = bias ? bias[col] : 0.f;
        #pragma unroll
        for(int mt=0;mt<2;mt++){
            const int row0 = bm+wm+mt*16+lg*4;
            #pragma unroll
            for(int r=0;r<4;r++){
                const int row = row0+r;
                float v = acc[mt][nt][r] + bv;
                if(RELU) v = fmaxf(v, 0.f);
                const size_t idx = TRANSOUT ? ((size_t)col*ldc + row) : ((size_t)row*ldc + col);
                C[idx] = f2b(v);
            }
        }
    }
}

// standalone wrapper (used for g2..g5)
template<bool TRANSOUT, bool RELU, bool AF32, bool BF32>
__global__ __launch_bounds__(256) void gemm64(
    const void* __restrict__ A, const void* __restrict__ B,
    const float* __restrict__ bias, u16* __restrict__ C,
    int M, int N, int K, int ldb, int ldc)
{
    __shared__ u16 As[2][64][40];
    __shared__ u16 Bs[2][64][40];
    gemm_body<TRANSOUT,RELU,AF32,BF32>(A,B,bias,C,M,N,K,ldb,ldc,blockIdx.x,blockIdx.y,As,Bs);
}

// ====== k_misc: three INDEPENDENT kernels in one launch (block-range dispatch) ======
// blocks [0,64): k_gcn (long blocks, start first); [64,320): g1 GEMM; [320,8512): G cvt.
// Previously serial (sum of times); now concurrent (≈max). Bodies verbatim -> bit-identical.
__global__ __launch_bounds__(256) void k_misc(
    const int* __restrict__ skill, const int* __restrict__ answer,
    const float* __restrict__ pos, const float* __restrict__ h1pre,
    const float* __restrict__ gcn_b1, const float* __restrict__ gcn_w2, const float* __restrict__ gcn_b2,
    const float* __restrict__ wih_dg, u16* __restrict__ pooled_proj,
    const float* __restrict__ G, u16* __restrict__ Gb,
    const float* __restrict__ stu, const float* __restrict__ hg_w1, const float* __restrict__ hg_b1,
    u16* __restrict__ tmpT)
{
    __shared__ u16 As[2][64][40];
    __shared__ u16 Bs[2][64][40];
    __shared__ int   sk[500];
    __shared__ float msk[500];
    __shared__ float coef[500];
    __shared__ float deg[101];
    __shared__ float agg1[101*8];
    __shared__ float agg2[101*8];
    __shared__ float red[256];
    __shared__ float vec8[8];
    __shared__ float sS[1];

    const int bid = blockIdx.x, tid = threadIdx.x;
    if(bid >= 320){
        // G cvt: f32 -> bf16, 8192 blocks x 2048 elems
        const size_t i = ((size_t)(bid-320)*256 + tid)*8;
        *(short8*)&Gb[i] = ld8f(G + i);
        return;
    }
    if(bid >= 64){
        // g1: tmpT = (stu @ hg_w1^T + hg_b1)^T   (4096x256, K=256), grid was (64,4)
        const int v = bid - 64;
        gemm_body<true,false,true,true>(stu, hg_w1, hg_b1, tmpT, 4096,256,256, 256, 4096,
                                        v&63, v>>6, As, Bs);
        return;
    }
    // ---- k_gcn body (b = bid), verbatim from R7 ----
    const int b = bid;
    for(int i=tid;i<500;i+=256){
        sk[i]=iclamp(skill[b*500+i],0,100);
        msk[i] = (answer[b*500+i]!=2)?1.f:0.f;
    }
    for(int i=tid;i<101;i+=256) deg[i]=1.f;           // self loop
    if(tid<8)  vec8[tid]=0.f;
    if(tid==8) sS[0]=0.f;
    __syncthreads();
    for(int e=tid;e<499;e+=256) atomicAdd(&deg[sk[e+1]], 1.f);
    __syncthreads();
    for(int i=tid;i<101;i+=256) deg[i] = rsqrtf(deg[i]);   // deg -> dinv
    float cnt=0.f; for(int i=tid;i<500;i+=256) cnt += msk[i];
    __syncthreads();
    red[tid]=cnt; __syncthreads();
    for(int s=128;s>0;s>>=1){ if(tid<s) red[tid]+=red[tid+s]; __syncthreads(); }
    const int len = iclamp((int)(red[0]+0.5f), 1, 500);
    __syncthreads();
    for(int i=tid;i<808;i+=256){ const int n=i>>3; agg1[i] = deg[n]*deg[n]*h1pre[i]; }
    __syncthreads();
    for(int i=tid;i<499*8;i+=256){
        const int e=i>>3, j=i&7, s=sk[e], d=sk[e+1];
        atomicAdd(&agg1[d*8+j], deg[s]*deg[d]*h1pre[s*8+j]);
    }
    __syncthreads();
    for(int i=tid;i<808;i+=256){ const int j=i&7; agg1[i] = fmaxf(agg1[i]+gcn_b1[j], 0.f); }
    __syncthreads();
    for(int i=tid;i<808;i+=256){ const int n=i>>3; agg2[i] = deg[n]*deg[n]*agg1[i]; }
    __syncthreads();
    for(int i=tid;i<499*8;i+=256){
        const int e=i>>3, j=i&7, s=sk[e], d=sk[e+1];
        atomicAdd(&agg2[d*8+j], deg[s]*deg[d]*agg1[s*8+j]);
    }
    const size_t prow = (size_t)(len-1)*500;
    float vmax = -1e30f;
    for(int i=tid;i<500;i+=256){ const float v = pos[prow+i]*msk[i]; coef[i]=v; vmax=fmaxf(vmax,v); }
    red[tid]=vmax; __syncthreads();           // also orders agg2 atomics
    for(int s=128;s>0;s>>=1){ if(tid<s) red[tid]=fmaxf(red[tid],red[tid+s]); __syncthreads(); }
    const float m = red[0]; __syncthreads();
    float lsum=0.f;
    for(int i=tid;i<500;i+=256){ const float e=__expf(coef[i]-m); coef[i]=e; lsum+=e; }
    red[tid]=lsum; __syncthreads();
    for(int s=128;s>0;s>>=1){ if(tid<s) red[tid]+=red[tid+s]; __syncthreads(); }
    const float inv = 1.f/red[0];
    __syncthreads();
    float v8[8]={0,0,0,0,0,0,0,0}; float ls=0.f;
    for(int i=tid;i<500;i+=256){
        const float ci = coef[i]*inv*msk[i];
        if(ci!=0.f){
            const int n=sk[i]; ls+=ci;
            #pragma unroll
            for(int j=0;j<8;j++) v8[j] += ci*agg2[n*8+j];
        }
    }
    #pragma unroll
    for(int j=0;j<8;j++) atomicAdd(&vec8[j], v8[j]);
    atomicAdd(&sS[0], ls);
    __syncthreads();
    {   // pooled row into LDS (red[])
        const int o = tid;
        float acc = gcn_b2[o]*sS[0];
        #pragma unroll
        for(int j=0;j<8;j++) acc += vec8[j]*gcn_w2[o*8+j];
        red[o] = acc;
    }
    __syncthreads();
    {   // fused k_pooledproj: pooled_proj[b][o] = pooled[b] . wih_dg[o][0:256]
        const int o = tid;
        const float* w = wih_dg + (size_t)o*768;
        float acc=0.f;
        for(int k=0;k<256;k+=4){
            f32x4 wv = *(const f32x4*)&w[k];
            acc += red[k]*wv.x + red[k+1]*wv.y + red[k+2]*wv.z + red[k+3]*wv.w;
        }
        pooled_proj[b*256+o]=f2b(acc);
    }
}

// ====== k_prep: fused independent prep — tables (606 blk) + idx (125 blk) + h1pre (8 blk) ======
__global__ __launch_bounds__(256) void k_prep(
    const float* __restrict__ skill_emb, const float* __restrict__ answer_emb,
    const float* __restrict__ wih_dg, const float* __restrict__ bih_dg, const float* __restrict__ bhh_dg,
    const float* __restrict__ wih_hg, const float* __restrict__ bih_hg, const float* __restrict__ bhh_hg,
    const float* __restrict__ gcn_w1,
    const int* __restrict__ skill, const int* __restrict__ answer, const int* __restrict__ student,
    float* __restrict__ table_dg, float* __restrict__ table_hg,
    float* __restrict__ h1pre, int* __restrict__ combo_t, int* __restrict__ sid_t)
{
    const int bid = blockIdx.x, tid = threadIdx.x;
    if(bid < 606){
        // table part: table[combo] = x(skill,answer) @ Wih[:,256:768]^T + bih + bhh
        const int which = (bid >= 303) ? 1 : 0;
        const int combo = bid - which*303;
        const float* wih = which ? wih_hg : wih_dg;
        const float* bih = which ? bih_hg : bih_dg;
        const float* bhh = which ? bhh_hg : bhh_dg;
        float* table     = which ? table_hg : table_dg;
        const int sid = combo/3, ans = combo - sid*3;
        __shared__ float sf[256], sg[256];
        sf[tid] = (ans==1) ? skill_emb[(size_t)sid*256+tid] : answer_emb[(size_t)ans*256+tid];
        sg[tid] = (ans==1) ? answer_emb[(size_t)ans*256+tid] : skill_emb[(size_t)sid*256+tid];
        __syncthreads();
        const int o = tid;
        float acc = bih[o] + bhh[o];
        const float* w = wih + (size_t)o*768;
        for(int k=0;k<256;k+=4){
            f32x4 w1v = *(const f32x4*)&w[256+k];
            f32x4 w2v = *(const f32x4*)&w[512+k];
            acc += sf[k]*w1v.x + sf[k+1]*w1v.y + sf[k+2]*w1v.z + sf[k+3]*w1v.w;
            acc += sg[k]*w2v.x + sg[k+1]*w2v.y + sg[k+2]*w2v.z + sg[k+3]*w2v.w;
        }
        table[(size_t)combo*256 + o] = acc;
    } else if(bid < 731){
        // idx part: combo/sid arrays, t-major, clamped
        const int i = (bid-606)*256 + tid;
        if(i>=32000) return;
        const int t = i>>6, b = i&63;
        const int sk = iclamp(skill[b*500+t], 0, 100);
        const int an = iclamp(answer[b*500+t], 0, 2);
        const int sd = iclamp(student[b*500+t]-1, 0, 4095);
        combo_t[i] = sk*3+an;
        sid_t[i]   = sd;
    } else {
        // h1pre part: skill_emb @ gcn_w1^T (101x8)
        if(tid >= 101) return;
        const int idx = (bid-731)*101 + tid;
        if(idx>=808) return;
        const int n=idx>>3, j=idx&7;
        const float* x = skill_emb + n*256;
        const float* w = gcn_w1 + j*256;
        float acc=0.f;
        for(int k=0;k<256;k+=4){
            f32x4 a = *(const f32x4*)&x[k];
            f32x4 b = *(const f32x4*)&w[k];
            acc += a.x*b.x + a.y*b.y + a.z*b.z + a.w*b.w;
        }
        h1pre[idx]=acc;
    }
}

// ====== k_pre: pre[rnn][t][b][c] = (table[combo] + proj) * C_TANH  (bf16, t-major) ======
// grid (500, 2, 4), block 256.
__global__ __launch_bounds__(256) void k_pre(
    const int* __restrict__ combo_t, const int* __restrict__ sid_t,
    const float* __restrict__ table_dg, const float* __restrict__ table_hg,
    const u16* __restrict__ pooled_proj, const u16* __restrict__ stu_proj,
    u16* __restrict__ pre_dg, u16* __restrict__ pre_hg)
{
    const int t = blockIdx.x, rnn = blockIdx.y, c = threadIdx.x;
    const int b0 = blockIdx.z*16;
    const float* tab = rnn ? table_hg : table_dg;
    u16* outp = rnn ? pre_hg : pre_dg;
    for(int b=b0;b<b0+16;b++){
        const int cmb = combo_t[t*64+b];
        const u16* prow = rnn ? (stu_proj + (size_t)sid_t[t*64+b]*256)
                              : (pooled_proj + (size_t)b*256);
        const float v = (tab[(size_t)cmb*256 + c] + b2f(prow[c])) * C_TANH;
        outp[((size_t)t*64+b)*256 + c] = f2b(v);
    }
}

// =============== RNN v6 (proven 366us): 16 waves, pre in MFMA C-init, ======
// scale folded into W, pointer strength-reduction. 8 blocks, wave = 16 cols.
__global__ __launch_bounds__(1024) void k_rnn(
    const u16* __restrict__ pre_dg, const u16* __restrict__ pre_hg,
    const float* __restrict__ whh_dg, const float* __restrict__ whh_hg,
    u16* __restrict__ hall_dg, u16* __restrict__ hall_hg)
{
    __shared__ u16 hc[2][8][4][16][8];    // 2 x 8KB, B-fragment chunk layout
    const int bid = blockIdx.x;
    const int rnn = bid>>2, grp = bid&3, rb = grp*16;
    const float* W   = rnn ? whh_hg : whh_dg;
    const u16*  pre  = rnn ? pre_hg : pre_dg;
    u16*        out  = rnn ? hall_hg : hall_dg;
    const int tid = threadIdx.x, wave = tid>>6, lane = tid&63;
    const int lm = lane&15, lg = lane>>4;
    const int cb = wave*16;

    // W fragments as A-operand (row = output col), register-resident, pre-scaled by C_TANH
    short8 wf[8];
    #pragma unroll
    for(int kk=0;kk<8;kk++)
        wf[kk] = ld8f_s(W + (size_t)(cb+lm)*256 + kk*32 + lg*8, C_TANH);

    for(int i=tid;i<2*8*4*16*8/2;i+=1024) ((unsigned*)hc)[i]=0;

    const size_t base = (size_t)(rb+lm)*256 + cb + lg*4;   // per-lane flat offset
    // LDS write slot (chunk layout): chunk = wave>>1, sub = (wave&1)*2+(lg>>1)
    const int wchunk = wave>>1, wsub = (wave&1)*2 + (lg>>1), wslot = (lg&1)*4;

    const u16* pp = pre + base;   // pre pointer, walks +16384 elems/step
    u16*       op = out + base;   // out pointer, walks +16384 elems/step
    uint2 pv = *(const uint2*)pp;
    pp += 16384;
    __syncthreads();

    auto stepf = [&](const u16 (&S)[8][4][16][8], u16 (&D)[8][4][16][8],
                     uint2 pvi, const u16* ppi, u16* opi)->uint2 {
        // C-init = pre (already scaled): saves the post-MFMA adds
        f32x4 a0, c0 = (f32x4){0.f,0.f,0.f,0.f};
        a0[0] = __uint_as_float(pvi.x << 16);
        a0[1] = __uint_as_float(pvi.x & 0xffff0000u);
        a0[2] = __uint_as_float(pvi.y << 16);
        a0[3] = __uint_as_float(pvi.y & 0xffff0000u);
        #pragma unroll
        for(int kk=0;kk<4;kk++){
            short8 hb = *(const short8*)&S[kk][lg][lm][0];
            a0 = __builtin_amdgcn_mfma_f32_16x16x32_bf16(wf[kk], hb, a0, 0,0,0);
        }
        #pragma unroll
        for(int kk=4;kk<8;kk++){
            short8 hb = *(const short8*)&S[kk][lg][lm][0];
            c0 = __builtin_amdgcn_mfma_f32_16x16x32_bf16(wf[kk], hb, c0, 0,0,0);
        }
        // prefetch next step's pre (t=500/501 reads stay inside the Gb allocation, never consumed)
        const uint2 pvn = *(const uint2*)ppi;
        float th[4];
        #pragma unroll
        for(int r=0;r<4;r++){
            const float x = a0[r] + c0[r];            // = c*(pre + W@h)
            const float e = fast_exp2(x);
            th[r] = fmaf(-2.f, __builtin_amdgcn_rcpf(e + 1.f), 1.f);
        }
        uint2 pk;
        asm("v_cvt_pk_bf16_f32 %0, %1, %2" : "=v"(pk.x) : "v"(th[0]), "v"(th[1]));
        asm("v_cvt_pk_bf16_f32 %0, %1, %2" : "=v"(pk.y) : "v"(th[2]), "v"(th[3]));
        *(uint2*)&D[wchunk][wsub][lm][wslot] = pk;
        *(uint2*)opi = pk;
        barrier_lds();      // LDS-visibility only: global loads/stores stay in flight
        return pvn;
    };

    for(int t=0;t<500;t+=2){
        pv = stepf(hc[0], hc[1], pv, pp, op);  pp += 16384; op += 16384;
        pv = stepf(hc[1], hc[0], pv, pp, op);  pp += 16384; op += 16384;
    }
}

// ====== theta = sigmoid(h_hg@w1^T + h_dg@w2^T + b1 + b2), dual-GEMM fused, bf16 out ======
// grid (250, 4), block 256.  M=32000, N=256, K=256.
__global__ __launch_bounds__(256) void k_theta(
    const u16* __restrict__ Ah, const u16* __restrict__ Ad,
    const float* __restrict__ w1, const float* __restrict__ w2,
    const float* __restrict__ b1, const float* __restrict__ b2,
    u16* __restrict__ theta)
{
    constexpr int BK=32;
    __shared__ u16 AsH[128][BK+8];
    __shared__ u16 AsD[128][BK+8];
    __shared__ u16 BsH[64][BK+8];
    __shared__ u16 BsD[64][BK+8];
    const int tid = threadIdx.x;
    const int bm = blockIdx.x*128, bn = blockIdx.y*64;
    const int wave = tid>>6, lane = tid&63, lm = lane&15, lg = lane>>4;
    const int wm = (wave>>1)*64, wn = (wave&1)*32;
    f32x4 acc[4][2];
    #pragma unroll
    for(int i=0;i<4;i++){ acc[i][0]=(f32x4){0.f,0.f,0.f,0.f}; acc[i][1]=(f32x4){0.f,0.f,0.f,0.f}; }

    const int arow0 = tid>>2, akc0 = (tid&3)*8;
    const int arow1 = arow0 + 64;
    for(int k0=0;k0<256;k0+=BK){
        *(short8*)&AsH[arow0][akc0] = ld8b(Ah + (size_t)(bm+arow0)*256 + k0+akc0);
        *(short8*)&AsH[arow1][akc0] = ld8b(Ah + (size_t)(bm+arow1)*256 + k0+akc0);
        *(short8*)&AsD[arow0][akc0] = ld8b(Ad + (size_t)(bm+arow0)*256 + k0+akc0);
        *(short8*)&AsD[arow1][akc0] = ld8b(Ad + (size_t)(bm+arow1)*256 + k0+akc0);
        *(short8*)&BsH[arow0][akc0] = ld8f(w1 + (size_t)(bn+arow0)*256 + k0+akc0);
        *(short8*)&BsD[arow0][akc0] = ld8f(w2 + (size_t)(bn+arow0)*256 + k0+akc0);
        __syncthreads();
        short8 afH[4], afD[4], bf1[2], bf2[2];
        #pragma unroll
        for(int mt=0;mt<4;mt++){
            afH[mt] = *(const short8*)&AsH[wm+mt*16+lm][lg*8];
            afD[mt] = *(const short8*)&AsD[wm+mt*16+lm][lg*8];
        }
        #pragma unroll
        for(int nt=0;nt<2;nt++){
            bf1[nt] = *(const short8*)&BsH[wn+nt*16+lm][lg*8];
            bf2[nt] = *(const short8*)&BsD[wn+nt*16+lm][lg*8];
        }
        #pragma unroll
        for(int nt=0;nt<2;nt++)
            #pragma unroll
            for(int mt=0;mt<4;mt++){
                acc[mt][nt] = __builtin_amdgcn_mfma_f32_16x16x32_bf16(afH[mt], bf1[nt], acc[mt][nt], 0,0,0);
                acc[mt][nt] = __builtin_amdgcn_mfma_f32_16x16x32_bf16(afD[mt], bf2[nt], acc[mt][nt], 0,0,0);
            }
        __syncthreads();
    }
    #pragma unroll
    for(int nt=0;nt<2;nt++){
        const int col = bn+wn+nt*16+lm;
        const float bb = b1[col]+b2[col];
        #pragma unroll
        for(int mt=0;mt<4;mt++){
            const int row0 = bm+wm+mt*16+lg*4;
            #pragma unroll
            for(int r=0;r<4;r++){
                const float x = acc[mt][nt][r] + bb;
                theta[(size_t)(row0+r)*256 + col] = f2b(1.f/(1.f+__expf(-x)));
            }
        }
    }
}

// =============== final gather: one wave per (b,t), three outputs ===============
__global__ __launch_bounds__(256) void k_out(
    const int* __restrict__ skill,
    const u16* __restrict__ hall_hg, const u16* __restrict__ hall_dg,
    const u16* __restrict__ theta,
    const float* __restrict__ fc_h_w, const float* __restrict__ fc_h_b,
    const float* __restrict__ fc_d_w, const float* __restrict__ fc_d_b,
    const float* __restrict__ fc_e_w, const float* __restrict__ fc_e_b,
    float* __restrict__ outp)
{
    const int tid=threadIdx.x, lane=tid&63;
    const int wid = blockIdx.x*4 + (tid>>6);        // 0..31935
    const int b = wid/499, t = wid - b*499;
    const int ns = skill[b*500 + t + 1];
    float o0=0.f,o1=0.f,o2=0.f,bh=0.f,bd=0.f,be=0.f;
    if(ns != 100){
        const int c = iclamp(ns, 0, 99);
        const size_t r = (size_t)t*64 + b;
        const int k = lane*4;
        short4v hh  = *(const short4v*)&hall_hg[r*256+k];
        short4v hd  = *(const short4v*)&hall_dg[r*256+k];
        short4v th  = *(const short4v*)&theta[r*256+k];
        f32x4 fh  = *(const f32x4*)&fc_h_w[(size_t)c*256+k];
        f32x4 fd  = *(const f32x4*)&fc_d_w[(size_t)c*256+k];
        f32x4 fe1 = *(const f32x4*)&fc_e_w[(size_t)c*512+k];
        f32x4 fe2 = *(const f32x4*)&fc_e_w[(size_t)c*512+256+k];
        #pragma unroll
        for(int j=0;j<4;j++){
            const float hhj=b2f((u16)hh[j]), hdj=b2f((u16)hd[j]), tj=b2f((u16)th[j]);
            o0 += hhj*fh[j];
            o1 += hdj*fd[j];
            o2 += tj*hhj*fe1[j] + (1.f-tj)*hdj*fe2[j];
        }
        #pragma unroll
        for(int off=32;off>0;off>>=1){
            o0 += __shfl_down(o0,off);
            o1 += __shfl_down(o1,off);
            o2 += __shfl_down(o2,off);
        }
        bh=fc_h_b[c]; bd=fc_d_b[c]; be=fc_e_b[c];
    }
    if(lane==0){
        outp[            b*499+t] = (ns==100)?0.f:(o0+bh);
        outp[31936     + b*499+t] = (ns==100)?0.f:(o1+bd);
        outp[2*31936   + b*499+t] = (ns==100)?0.f:(o2+be);
    }
}

// ================================= launch =================================
extern "C" void kernel_launch(void* const* d_in, const int* in_sizes, int n_in,
                              void* d_out, int out_size, void* d_ws, size_t ws_size,
                              hipStream_t stream)
{
    const int* student = (const int*)d_in[0];
    const int* skill   = (const int*)d_in[1];
    const int* answer  = (const int*)d_in[2];
    const float* G        = (const float*)d_in[3];
    const float* skill_emb= (const float*)d_in[4];
    const float* answer_emb=(const float*)d_in[5];
    const float* stu      = (const float*)d_in[6];
    const float* hg_w1    = (const float*)d_in[7];
    const float* hg_b1    = (const float*)d_in[8];
    const float* hg_w2    = (const float*)d_in[9];
    const float* hg_b2    = (const float*)d_in[10];
    const float* gcn_w1   = (const float*)d_in[11];
    const float* gcn_b1   = (const float*)d_in[12];
    const float* gcn_w2   = (const float*)d_in[13];
    const float* gcn_b2   = (const float*)d_in[14];
    const float* w1_w     = (const float*)d_in[15];
    const float* w1_b     = (const float*)d_in[16];
    const float* w2_w     = (const float*)d_in[17];
    const float* w2_b     = (const float*)d_in[18];
    const float* fc_d_w   = (const float*)d_in[19];
    const float* fc_d_b   = (const float*)d_in[20];
    const float* fc_h_w   = (const float*)d_in[21];
    const float* fc_h_b   = (const float*)d_in[22];
    const float* fc_e_w   = (const float*)d_in[23];
    const float* fc_e_b   = (const float*)d_in[24];
    const float* pos      = (const float*)d_in[25];
    const float* dg_wih   = (const float*)d_in[26];
    const float* dg_whh   = (const float*)d_in[27];
    const float* dg_bih   = (const float*)d_in[28];
    const float* dg_bhh   = (const float*)d_in[29];
    const float* hgr_wih  = (const float*)d_in[30];
    const float* hgr_whh  = (const float*)d_in[31];
    const float* hgr_bih  = (const float*)d_in[32];
    const float* hgr_bhh  = (const float*)d_in[33];

    char* ws = (char*)d_ws;
    size_t off = 0;
    auto nxt = [&](size_t bytes)->char*{
        char* r = ws + off;
        off += (bytes + 255) & ~(size_t)255;
        return r;
    };
    float* h1pre      = (float*)nxt(808*4);
    float* table_dg   = (float*)nxt(303*256*4);
    float* table_hg   = (float*)nxt(303*256*4);
    u16*   tmpT       = (u16*)  nxt((size_t)256*4096*2);
    u16*   hbuf       = (u16*)  nxt((size_t)4096*256*2);
    u16*   stu_proj   = (u16*)  nxt((size_t)4096*256*2);
    u16*   pooled_proj= (u16*)  nxt(64*256*2);
    int*   combo_t    = (int*)  nxt(32000*4);
    int*   sid_t      = (int*)  nxt(32000*4);
    u16*   Gb         = (u16*)  nxt((size_t)4096*4096*2);   // 33.6 MB; dead after gemm#4
    u16*   hall_dg    = (u16*)  nxt((size_t)32000*256*2);   // 16.4 MB
    u16*   hall_hg    = (u16*)  nxt((size_t)32000*256*2);   // 16.4 MB
    // overlays on Gb (Gb dead before k_pre writes these):
    u16*   pre_dg     = Gb;
    u16*   pre_hg     = Gb + (size_t)32000*256;
    u16*   theta      = pre_dg;                              // pre_dg dead after k_rnn

    // fused prep (tables + idx + h1pre)
    k_prep<<<739,256,0,stream>>>(skill_emb, answer_emb,
                                 dg_wih, dg_bih, dg_bhh,
                                 hgr_wih, hgr_bih, hgr_bhh,
                                 gcn_w1, skill, answer, student,
                                 table_dg, table_hg, h1pre, combo_t, sid_t);
    // fused independent trio: gcn (64) + g1 (256) + G cvt (8192)
    k_misc<<<8512,256,0,stream>>>(skill, answer, pos, h1pre, gcn_b1, gcn_w2, gcn_b2,
                                  dg_wih, pooled_proj,
                                  G, Gb,
                                  stu, hg_w1, hg_b1, tmpT);

    // remaining GCN chain (dbuf single-barrier gemm64, bf16 Gb reads)
    gemm64<false,true ,false,false><<<dim3(64,4),256,0,stream>>>(Gb,   tmpT,  nullptr, hbuf, 4096,256,4096, 4096, 256);
    gemm64<true ,false,false,true ><<<dim3(64,4),256,0,stream>>>(hbuf, hg_w2, hg_b2, tmpT, 4096,256,256,  256, 4096);
    gemm64<false,false,false,false><<<dim3(64,4),256,0,stream>>>(Gb,   tmpT,  nullptr, hbuf, 4096,256,4096, 4096, 256);
    gemm64<false,false,false,true ><<<dim3(64,4),256,0,stream>>>(hbuf, hgr_wih, nullptr, stu_proj, 4096,256,256, 768, 256);

    // fused pre-activation array (t-major bf16, pre-scaled by 2*log2e) — overwrites Gb (dead)
    k_pre<<<dim3(500,2,4),256,0,stream>>>(combo_t, sid_t, table_dg, table_hg,
                                          pooled_proj, stu_proj, pre_dg, pre_hg);

    // recurrences
    k_rnn<<<8,1024,0,stream>>>(pre_dg, pre_hg, dg_whh, hgr_whh, hall_dg, hall_hg);

    // theta + outputs
    k_theta<<<dim3(250,4),256,0,stream>>>(hall_hg, hall_dg, w1_w, w2_w, w1_b, w2_b, theta);
    k_out<<<7984,256,0,stream>>>(skill, hall_hg, hall_dg, theta,
                                 fc_h_w, fc_h_b, fc_d_w, fc_d_b, fc_e_w, fc_e_b,
                                 (float*)d_out);
}